// Round 23
// baseline (599.331 us; speedup 1.0000x reference)
//
#include <hip/hip_runtime.h>
#include <hip/hip_bf16.h>

// TensorConvLayer: edge MLP (bf16 MFMA) -> tensor product (in-register) ->
// ticketed sorted-row emit (1 int atomic/edge) -> coalesced node gather -> BN.
//
// R22 -> R23: conflict fix landed on the counter (12M->2M) but time -4% --
// conflicts were hidden. Still latency-bound at 2 waves/SIMD (LDS-capped
// 1 block/CU). Fix: 1024-thread blocks (16 waves) + xg demoted to bf16 so
// everything fits 160KB LDS: 73.7(W2)+8.2(W1)+2.5(b)+36.9(hlds)+34.8(xg)
// = 152.5KB -> 4 waves/SIMD (2x latency hiding). bf16 TP coefficients add
// ~0.4% rel error (absmax ~+0.03, margin ample). Rest = green R22.

typedef __bf16 bf16_t;
typedef bf16_t bf16x8 __attribute__((ext_vector_type(8)));
typedef bf16_t bf16x4 __attribute__((ext_vector_type(4)));
typedef float  f32x4  __attribute__((ext_vector_type(4)));

#define NREP 32   // stats replicas

__device__ __forceinline__ bf16_t f2bf(float f) {
  unsigned u = __builtin_bit_cast(unsigned, f);
  u += 0x7fffu + ((u >> 16) & 1u);          // round-to-nearest-even
  unsigned short s = (unsigned short)(u >> 16);
  return __builtin_bit_cast(bf16_t, s);
}
__device__ __forceinline__ float bf2f(bf16_t b) {
  unsigned u = ((unsigned)__builtin_bit_cast(unsigned short, b)) << 16;
  return __builtin_bit_cast(float, u);
}

#define MFMA16(a, b, c) __builtin_amdgcn_mfma_f32_16x16x32_bf16((a), (b), (c), 0, 0, 0)

// ---------------------------------------------------------------- zero ----
__global__ __launch_bounds__(256) void tcl_zero(
    int* __restrict__ cnt, int* __restrict__ pos, float* __restrict__ statsrep,
    float* __restrict__ statsfin, int NN)
{
  int t = blockIdx.x * 256 + threadIdx.x;
  if (t < NN) { cnt[t] = 0; pos[t] = 0; }
  if (t < NREP * 64) statsrep[t] = 0.f;
  if (t < 64) statsfin[t] = 0.f;
}

// ------------------------------------------------------- count + wprep ----
// Weights emitted FRAGMENT-MAJOR: elem t = ((((mf*2+half)*4+kg)*16)+l15)*8+e
// holds W[k][n] with n = 16*mf + l15, k = half*32 + kg*8 + e.
__global__ __launch_bounds__(256) void tcl_count(
    const int* __restrict__ eidx, const float* __restrict__ w1,
    const float* __restrict__ w2, unsigned short* __restrict__ w1tg,
    unsigned short* __restrict__ w2tg, int* __restrict__ cnt, int E)
{
  int t = blockIdx.x * 256 + threadIdx.x;
  if (t < E) atomicAdd(&cnt[eidx[E + t]], 1);
  if (t < 64 * 64) {
    int e = t & 7, l15 = (t >> 3) & 15, kg = (t >> 7) & 3, half = (t >> 9) & 1, mf = t >> 10;
    int n = 16 * mf + l15, k = half * 32 + kg * 8 + e;
    w1tg[t] = __builtin_bit_cast(unsigned short, f2bf(w1[k * 64 + n]));
  }
  if (t < 576 * 64) {
    int e = t & 7, l15 = (t >> 3) & 15, kg = (t >> 7) & 3, half = (t >> 9) & 1, mf = t >> 10;
    int n = 16 * mf + l15, k = half * 32 + kg * 8 + e;
    w2tg[t] = __builtin_bit_cast(unsigned short, f2bf(w2[k * 576 + n]));
  }
}

// ---------------------------------------------------------------- scan ----
__global__ __launch_bounds__(1024) void tcl_scan_a(
    const int* __restrict__ cnt, int* __restrict__ excl,
    int* __restrict__ bsum, int NN)
{
  __shared__ int sm[1024];
  int i = blockIdx.x * 1024 + threadIdx.x;
  int v = (i < NN) ? cnt[i] : 0;
  sm[threadIdx.x] = v;
  __syncthreads();
#pragma unroll
  for (int off = 1; off < 1024; off <<= 1) {
    int t = (threadIdx.x >= off) ? sm[threadIdx.x - off] : 0;
    __syncthreads();
    sm[threadIdx.x] += t;
    __syncthreads();
  }
  if (i < NN) excl[i] = sm[threadIdx.x] - v;
  if (threadIdx.x == 1023) bsum[blockIdx.x] = sm[threadIdx.x];
}

__global__ __launch_bounds__(128) void tcl_scan_b(int* __restrict__ bsum, int nb)
{
  __shared__ int sm[128];
  int t = threadIdx.x;
  int v = (t < nb) ? bsum[t] : 0;
  sm[t] = v;
  __syncthreads();
#pragma unroll
  for (int off = 1; off < 128; off <<= 1) {
    int u = (t >= off) ? sm[t - off] : 0;
    __syncthreads();
    sm[t] += u;
    __syncthreads();
  }
  if (t < nb) bsum[t] = sm[t] - v;
}

__global__ __launch_bounds__(256) void tcl_scan_c(
    const int* __restrict__ excl, const int* __restrict__ bsum,
    int* __restrict__ roff, int NN)
{
  int i = blockIdx.x * 256 + threadIdx.x;
  if (i < NN) roff[i] = excl[i] + bsum[i >> 10];
}

// ---------------------------------------------------------------- edge ----
// 1024 threads = 16 autonomous waves, 16 edges each. Weights staged in LDS
// fragment-major (zero-conflict sequential ds_read_b128); one barrier.
template <bool SORTED>
__global__ __launch_bounds__(1024) void tcl_edge(
    const float* __restrict__ atom, const float* __restrict__ efeat,
    const float* __restrict__ esh, const int* __restrict__ eidx,
    const float* __restrict__ b1, const float* __restrict__ b2,
    const unsigned short* __restrict__ w1tg, const unsigned short* __restrict__ w2tg,
    float* __restrict__ outbuf, int* __restrict__ pos,
    const int* __restrict__ roff, int* __restrict__ cnt, int E)
{
  // ~152.5KB LDS -> 1 block/CU, 16 waves (4/SIMD).
  __shared__ __attribute__((aligned(16))) bf16_t w2l[576 * 64];
  __shared__ __attribute__((aligned(16))) bf16_t w1l[64 * 64];
  __shared__ __attribute__((aligned(16))) float  b2l[576];
  __shared__ __attribute__((aligned(16))) float  b1l[64];
  __shared__ __attribute__((aligned(16))) bf16_t hlds[16][16][72];
  __shared__ __attribute__((aligned(16))) bf16_t xg[16][16][68];

  const int tid  = threadIdx.x;
  const int wv   = tid >> 6;      // wave 0..15 (independent after staging)
  const int lane = tid & 63;
  const int l15  = lane & 15;     // edge in group
  const int kg   = lane >> 4;     // K-slice 0..3
  const int kh   = kg >> 1;
  const int fo   = (l15 << 3);    // fragment elem offset within 128-chunk

  // ---- stage weights once per block (linear dword copy) ----
  {
    const unsigned* s2 = (const unsigned*)w2tg;
    unsigned* d2 = (unsigned*)w2l;
    for (int i = tid; i < 576 * 32; i += 1024) d2[i] = s2[i];
    const unsigned* s1 = (const unsigned*)w1tg;
    unsigned* d1 = (unsigned*)w1l;
    for (int i = tid; i < 64 * 32; i += 1024) d1[i] = s1[i];
    if (tid < 576) b2l[tid] = b2[tid];
    if (tid < 64) b1l[tid] = b1[tid];
  }
  __syncthreads();                 // the ONLY barrier

  const int ngr = (E + 15) >> 4;
  const int gw0 = blockIdx.x * 16 + wv;
  const int gstride = gridDim.x * 16;

  for (int g = gw0; g < ngr; g += gstride) {
    long ge = (long)g * 16 + l15;
    bool v = ge < E;

    // ---- A: efeat -> B-fragments direct from global (full K=64 row) ----
    bf16x8 Bf0, Bf1;
    {
      float4 a = {0,0,0,0}, b = a, c = a, d = a;
      if (v) {
        const float4* p = (const float4*)(efeat + ge * 64 + kg * 8);
        a = p[0]; b = p[1];
        const float4* q = (const float4*)(efeat + ge * 64 + 32 + kg * 8);
        c = q[0]; d = q[1];
      }
      Bf0[0]=f2bf(a.x); Bf0[1]=f2bf(a.y); Bf0[2]=f2bf(a.z); Bf0[3]=f2bf(a.w);
      Bf0[4]=f2bf(b.x); Bf0[5]=f2bf(b.y); Bf0[6]=f2bf(b.z); Bf0[7]=f2bf(b.w);
      Bf1[0]=f2bf(c.x); Bf1[1]=f2bf(c.y); Bf1[2]=f2bf(c.z); Bf1[3]=f2bf(c.w);
      Bf1[4]=f2bf(d.x); Bf1[5]=f2bf(d.y); Bf1[6]=f2bf(d.z); Bf1[7]=f2bf(d.w);
    }

    // ---- B: premultiplied TP coefficient table (bf16, work split by kg) ----
    //  [0:16) x0 | [16:40) x1*sh0*c11 | [40:48) (x1.sh1)*c10
    //  [48:64) x0*sh0*c00 | [64:67) sh1*c01
    if (v) {
      int dst = eidx[ge];
      const float* xr = atom + (long)dst * 40;
      const float inv_s2 = 0.70710678118654752f;
      if (kg == 0) {
        for (int i = 0; i < 16; ++i) xg[wv][l15][i] = f2bf(xr[i]);
      } else if (kg == 1) {
        float k11 = esh[ge * 4] * inv_s2 * 0.35355339059327378f;
        for (int t2 = 0; t2 < 24; ++t2) xg[wv][l15][16 + t2] = f2bf(xr[16 + t2] * k11);
      } else if (kg == 2) {
        float s1x = esh[ge * 4 + 1], s1y = esh[ge * 4 + 2], s1z = esh[ge * 4 + 3];
        float k10 = inv_s2 * 0.20412414523193150f;
        for (int i = 0; i < 8; ++i) {
          float y = xr[16 + 3 * i] * s1x + xr[17 + 3 * i] * s1y + xr[18 + 3 * i] * s1z;
          xg[wv][l15][40 + i] = f2bf(y * k10);
        }
        float ks = inv_s2 * 0.25f;
        xg[wv][l15][64] = f2bf(s1x * ks);
        xg[wv][l15][65] = f2bf(s1y * ks);
        xg[wv][l15][66] = f2bf(s1z * ks);
      } else {
        float k0s = esh[ge * 4] * inv_s2 * 0.25f;
        for (int i = 0; i < 16; ++i) xg[wv][l15][48 + i] = f2bf(xr[i] * k0s);
      }
    }

    // ---- C: GEMM1  h = relu(W1T . ef + b1); fragment-major LDS reads ----
    for (int mf = 0; mf < 4; ++mf) {
      bf16x8 a0 = *(const bf16x8*)(w1l + ((mf * 8 + kg) << 7) + fo);
      bf16x8 a1 = *(const bf16x8*)(w1l + ((mf * 8 + 4 + kg) << 7) + fo);
      f32x4 acc = {0.f, 0.f, 0.f, 0.f};
      acc = MFMA16(a0, Bf0, acc);
      acc = MFMA16(a1, Bf1, acc);
      int j0 = 16 * mf + 4 * kg;   // C/D: col=lane&15 (edge), row=(lane>>4)*4+r
      bf16x4 hv;
#pragma unroll
      for (int r = 0; r < 4; ++r) {
        float x = acc[r] + b1l[j0 + r];
        x = x > 0.f ? x : 0.f;
        hv[r] = f2bf(x);
      }
      *(bf16x4*)&hlds[wv][l15][j0] = hv;
    }

    // ---- D: re-read h as B-fragments (same wave; lgkmcnt ordering) ----
    bf16x8 Bh0 = *(const bf16x8*)&hlds[wv][l15][kg * 8];
    bf16x8 Bh1 = *(const bf16x8*)&hlds[wv][l15][32 + kg * 8];
    float s0 = bf2f(xg[wv][l15][64]), s1 = bf2f(xg[wv][l15][65]), s2 = bf2f(xg[wv][l15][66]);

    // ---- E: GEMM2 + TP; fragment-major zero-conflict weight reads ----
    float o0[4] = {};        // out0 slice j = 4*kg + r (complete per lane)
    float o1[4][3] = {};     // out1 slice j = 4*(kg&1) + r (partial: this kh)

    for (int mf = 0; mf < 16; ++mf) {          // w00: i=mf, j=4*kg+r
      bf16x8 a0 = *(const bf16x8*)(w2l + ((mf * 8 + kg) << 7) + fo);
      bf16x8 a1 = *(const bf16x8*)(w2l + ((mf * 8 + 4 + kg) << 7) + fo);
      f32x4 bv = *(const f32x4*)&b2l[16 * mf + 4 * kg];
      f32x4 acc = {0.f, 0.f, 0.f, 0.f};
      acc = MFMA16(a0, Bh0, acc);
      acc = MFMA16(a1, Bh1, acc);
      float cA = bf2f(xg[wv][l15][48 + mf]);
#pragma unroll
      for (int r = 0; r < 4; ++r) o0[r] += (acc[r] + bv[r]) * cA;
    }
    for (int mf = 16; mf < 20; ++mf) {         // w11: i=2*(mf-16)+kh, j=4*(kg&1)+r
      bf16x8 a0 = *(const bf16x8*)(w2l + ((mf * 8 + kg) << 7) + fo);
      bf16x8 a1 = *(const bf16x8*)(w2l + ((mf * 8 + 4 + kg) << 7) + fo);
      f32x4 bv = *(const f32x4*)&b2l[16 * mf + 4 * kg];
      f32x4 acc = {0.f, 0.f, 0.f, 0.f};
      acc = MFMA16(a0, Bh0, acc);
      acc = MFMA16(a1, Bh1, acc);
      int i = 2 * (mf - 16) + kh;
      float c0 = bf2f(xg[wv][l15][16 + 3 * i]), c1 = bf2f(xg[wv][l15][17 + 3 * i]), c2 = bf2f(xg[wv][l15][18 + 3 * i]);
#pragma unroll
      for (int r = 0; r < 4; ++r) {
        float wA = acc[r] + bv[r];
        o1[r][0] += wA * c0; o1[r][1] += wA * c1; o1[r][2] += wA * c2;
      }
    }
    for (int mf = 20; mf < 28; ++mf) {         // w01: i=2*(mf-20)+kh, j=4*(kg&1)+r
      bf16x8 a0 = *(const bf16x8*)(w2l + ((mf * 8 + kg) << 7) + fo);
      bf16x8 a1 = *(const bf16x8*)(w2l + ((mf * 8 + 4 + kg) << 7) + fo);
      f32x4 bv = *(const f32x4*)&b2l[16 * mf + 4 * kg];
      f32x4 acc = {0.f, 0.f, 0.f, 0.f};
      acc = MFMA16(a0, Bh0, acc);
      acc = MFMA16(a1, Bh1, acc);
      int i = 2 * (mf - 20) + kh;
      float xA = bf2f(xg[wv][l15][i]);
#pragma unroll
      for (int r = 0; r < 4; ++r) {
        float tA = (acc[r] + bv[r]) * xA;
        o1[r][0] += tA * s0; o1[r][1] += tA * s1; o1[r][2] += tA * s2;
      }
    }
    for (int mf = 28; mf < 36; ++mf) {         // w10: i=mf-28, j=4*kg+r
      bf16x8 a0 = *(const bf16x8*)(w2l + ((mf * 8 + kg) << 7) + fo);
      bf16x8 a1 = *(const bf16x8*)(w2l + ((mf * 8 + 4 + kg) << 7) + fo);
      f32x4 bv = *(const f32x4*)&b2l[16 * mf + 4 * kg];
      f32x4 acc = {0.f, 0.f, 0.f, 0.f};
      acc = MFMA16(a0, Bh0, acc);
      acc = MFMA16(a1, Bh1, acc);
      float cA = bf2f(xg[wv][l15][40 + mf - 28]);
#pragma unroll
      for (int r = 0; r < 4; ++r) o0[r] += (acc[r] + bv[r]) * cA;
    }

    // fold kh pairs (lane^32: kg<->kg^2, same l15); lanes kg<2 hold full o1
    float o1f[4][3];
#pragma unroll
    for (int r = 0; r < 4; ++r)
#pragma unroll
      for (int c = 0; c < 3; ++c)
        o1f[r][c] = o1[r][c] + __shfl_xor(o1[r][c], 32);

    // ---- F: emit ----
    if (SORTED) {
      int dstrow = 0;
      if (v && kg == 0) {
        int src = eidx[E + ge];
        dstrow = roff[src] + atomicAdd(&pos[src], 1);
      }
      dstrow = __shfl(dstrow, l15);      // lane l15 holds kg==0's ticket
      if (v) {
        float* orow = outbuf + (long)dstrow * 40;
        f32x4 v0 = {o0[0], o0[1], o0[2], o0[3]};
        *(f32x4*)(orow + 4 * kg) = v0;
        if (kg < 2) {
          f32x4 u0 = {o1f[0][0], o1f[0][1], o1f[0][2], o1f[1][0]};
          f32x4 u1 = {o1f[1][1], o1f[1][2], o1f[2][0], o1f[2][1]};
          f32x4 u2 = {o1f[2][2], o1f[3][0], o1f[3][1], o1f[3][2]};
          float* ob = orow + 16 + 12 * kg;
          *(f32x4*)(ob + 0) = u0;
          *(f32x4*)(ob + 4) = u1;
          *(f32x4*)(ob + 8) = u2;
        }
      }
    } else {
      if (v) {
        int src = eidx[E + ge];
        float* srow = outbuf + (long)src * 40;
#pragma unroll
        for (int r = 0; r < 4; ++r) unsafeAtomicAdd(&srow[4 * kg + r], o0[r]);
        if (kg < 2) {
          int j1 = 4 * kg;
#pragma unroll
          for (int r = 0; r < 4; ++r)
#pragma unroll
            for (int c = 0; c < 3; ++c)
              unsafeAtomicAdd(&srow[16 + 3 * (j1 + r) + c], o1f[r][c]);
        }
      }
    }
  }
}

// -------------------------------------------------------- node (gather) ----
// stats atomics striped over NREP replicas (contention /32) + in-wave 3:1
// vsq fold (8 atomics instead of 24 for v channels).
__global__ __launch_bounds__(256) void tcl_node2(
    const float* __restrict__ atom, const float* __restrict__ tp,
    const int* __restrict__ roff, const int* __restrict__ cnt,
    float* __restrict__ out, float* __restrict__ statsrep, int NN)
{
  int lane = threadIdx.x & 63;
  int gw = blockIdx.x * 4 + (threadIdx.x >> 6);
  int stride = gridDim.x * 4;
  float ssum = 0.f, ssq = 0.f, vsq = 0.f;
  for (int n = gw; n < NN; n += stride) {
    int deg = cnt[n];
    long base = roff[n];
    if (lane < 40) {
      float acc = 0.f;
      for (int d = 0; d < deg; ++d) acc += tp[(base + d) * 40 + lane];
      float c = deg > 0 ? (float)deg : 1.f;
      long idx = (long)n * 40 + lane;
      float o = acc / c + atom[idx];
      out[idx] = o;
      if (lane < 16) { ssum += o; ssq += o * o; }
      else           { vsq += o * o; }
    }
  }
  float* srep = statsrep + (long)(blockIdx.x & (NREP - 1)) * 64;
  // fold 3 vector components in-wave: lane 16+3m collects 16+3m+1, 16+3m+2
  float va = __shfl(vsq, lane + 1);
  float vb = __shfl(vsq, lane + 2);
  if (lane < 16) {
    unsafeAtomicAdd(&srep[lane], ssum);
    unsafeAtomicAdd(&srep[16 + lane], ssq);
  } else if (lane < 40 && (lane - 16) % 3 == 0) {
    unsafeAtomicAdd(&srep[32 + (lane - 16) / 3], (vsq + va) + vb);
  }
}

// ------------------------------------------------------------ collapse ----
__global__ __launch_bounds__(64) void tcl_collapse(
    const float* __restrict__ statsrep, float* __restrict__ statsfin)
{
  int c = threadIdx.x;
  float s = 0.f;
  for (int r = 0; r < NREP; ++r) s += statsrep[(long)r * 64 + c];
  statsfin[c] = s;
}

// ---------------------------------------------------- node (atomic path) ----
__global__ __launch_bounds__(256) void tcl_node(
    const float* __restrict__ atom, const int* __restrict__ cnt,
    float* __restrict__ out, float* __restrict__ stats, int NN)
{
  int lane = threadIdx.x & 63;
  int gw = blockIdx.x * 4 + (threadIdx.x >> 6);
  int stride = gridDim.x * 4;
  float ssum = 0.f, ssq = 0.f, vsq = 0.f;
  for (int r = gw; r < NN; r += stride) {
    float c = (float)cnt[r];
    c = c > 1.f ? c : 1.f;
    if (lane < 40) {
      long idx = (long)r * 40 + lane;
      float o = out[idx] / c + atom[idx];
      out[idx] = o;
      if (lane < 16) { ssum += o; ssq += o * o; }
      else           { vsq += o * o; }
    }
  }
  if (lane < 16) {
    unsafeAtomicAdd(&stats[lane], ssum);
    unsafeAtomicAdd(&stats[16 + lane], ssq);
  } else if (lane < 40) {
    unsafeAtomicAdd(&stats[32 + (lane - 16) / 3], vsq);
  }
}

// ---------------------------------------------------------------- norm ----
__global__ __launch_bounds__(256) void tcl_norm(
    float* __restrict__ out, const float* __restrict__ stats,
    const float* __restrict__ bnw, const float* __restrict__ bnb, int NN)
{
  long idx = (long)blockIdx.x * 256 + threadIdx.x;
  long tot = (long)NN * 40;
  if (idx >= tot) return;
  int c = (int)(idx % 40);
  float o = out[idx];
  float invN = 1.0f / (float)NN;
  if (c < 16) {
    float mean = stats[c] * invN;
    float var  = stats[16 + c] * invN - mean * mean;
    float rs   = rsqrtf(var + 1e-5f);
    o = (o - mean) * rs * bnw[c] + bnb[c];
  } else {
    int m = (c - 16) / 3;
    float vn = stats[32 + m] * invN * (1.0f / 3.0f);
    float rs = rsqrtf(vn + 1e-5f);
    o = o * rs * bnw[16 + m];
  }
  out[idx] = o;
}

// -------------------------------------------------------------- launch ----
extern "C" void kernel_launch(void* const* d_in, const int* in_sizes, int n_in,
                              void* d_out, int out_size, void* d_ws, size_t ws_size,
                              hipStream_t stream)
{
  const float* atom  = (const float*)d_in[0];
  const float* efeat = (const float*)d_in[1];
  const float* esh   = (const float*)d_in[2];
  const int*   eidx  = (const int*)d_in[3];
  const float* w1    = (const float*)d_in[4];
  const float* b1    = (const float*)d_in[5];
  const float* w2    = (const float*)d_in[6];
  const float* b2    = (const float*)d_in[7];
  const float* bnw   = (const float*)d_in[8];
  const float* bnb   = (const float*)d_in[9];
  int E  = in_sizes[3] / 2;
  int NN = in_sizes[0] / 40;
  float* out = (float*)d_out;

  // workspace layout (~81.7MB for E=500k, NN=100k; proven fit in R2/R17)
  size_t off = 0;
  auto align256 = [&](size_t o) { return (o + 255) & ~(size_t)255; };
  int* cnt = (int*)d_ws;                                   off += (size_t)NN * 4;
  off = align256(off);
  int* pos = (int*)((char*)d_ws + off);                    off += (size_t)NN * 4;
  off = align256(off);
  int* excl = (int*)((char*)d_ws + off);                   off += (size_t)NN * 4;
  off = align256(off);
  int* bsum = (int*)((char*)d_ws + off);                   off += 128 * 4;
  off = align256(off);
  int* roff = (int*)((char*)d_ws + off);                   off += (size_t)NN * 4;
  off = align256(off);
  float* statsrep = (float*)((char*)d_ws + off);           off += (size_t)NREP * 64 * 4;
  off = align256(off);
  float* statsfin = (float*)((char*)d_ws + off);           off += 64 * 4;
  off = align256(off);
  unsigned short* w1tg = (unsigned short*)((char*)d_ws + off); off += 64 * 64 * 2;
  off = align256(off);
  unsigned short* w2tg = (unsigned short*)((char*)d_ws + off); off += 576 * 64 * 2;
  off = align256(off);
  float* tp = (float*)((char*)d_ws + off);
  size_t need = off + (size_t)E * 40 * 4;

  int nb = (NN + 1023) / 1024;   // scan chunks (<=128)
  bool sorted = (ws_size >= need) && (nb <= 128);

  tcl_zero<<<(NN + 255) / 256, 256, 0, stream>>>(cnt, pos, statsrep, statsfin, NN);
  tcl_count<<<(E + 255) / 256, 256, 0, stream>>>(eidx, w1, w2, w1tg, w2tg, cnt, E);

  if (sorted) {
    tcl_scan_a<<<nb, 1024, 0, stream>>>(cnt, excl, bsum, NN);
    tcl_scan_b<<<1, 128, 0, stream>>>(bsum, nb);
    tcl_scan_c<<<(NN + 255) / 256, 256, 0, stream>>>(excl, bsum, roff, NN);
    tcl_edge<true><<<512, 1024, 0, stream>>>(atom, efeat, esh, eidx, b1, b2,
                                             w1tg, w2tg, tp, pos, roff, cnt, E);
    tcl_node2<<<1024, 256, 0, stream>>>(atom, tp, roff, cnt, out, statsrep, NN);
    tcl_collapse<<<1, 64, 0, stream>>>(statsrep, statsfin);
  } else {
    hipMemsetAsync(d_out, 0, (size_t)NN * 40 * sizeof(float), stream);
    tcl_edge<false><<<512, 1024, 0, stream>>>(atom, efeat, esh, eidx, b1, b2,
                                              w1tg, w2tg, out, pos, roff, cnt, E);
    tcl_node<<<256, 256, 0, stream>>>(atom, cnt, out, statsfin, NN);
  }
  tcl_norm<<<(int)(((long)NN * 40 + 255) / 256), 256, 0, stream>>>(out, statsfin, bnw, bnb, NN);
}

// Round 24
// 482.653 us; speedup vs baseline: 1.2417x; 1.2417x over previous
//
#include <hip/hip_runtime.h>
#include <hip/hip_bf16.h>

// TensorConvLayer: edge MLP (bf16 MFMA) -> tensor product (in-register) ->
// ticketed sorted-row emit (1 int atomic/edge) -> coalesced node gather -> BN.
//
// R23 -> R24: R23's 1024-thread block forced VGPR 128->64 (launch_bounds
// register squeeze, same failure family as R3/R4/R11) -> ~1.4GB scratch
// spill traffic, edge 490us. Split the difference: 768 threads = 12 waves
// (3/SIMD). VGPR budget ~170 >= compiler's natural 128 -> no spill;
// occupancy 1.5x R22. LDS w/ bf16 xg (absmax-neutral, proven R23):
// 84.5 + 27.6(hlds) + 26.1(xg) = 138.2KB. Rest = green R22 mapping.

typedef __bf16 bf16_t;
typedef bf16_t bf16x8 __attribute__((ext_vector_type(8)));
typedef bf16_t bf16x4 __attribute__((ext_vector_type(4)));
typedef float  f32x4  __attribute__((ext_vector_type(4)));

#define NREP 32   // stats replicas
#define NWV  12   // waves per edge block

__device__ __forceinline__ bf16_t f2bf(float f) {
  unsigned u = __builtin_bit_cast(unsigned, f);
  u += 0x7fffu + ((u >> 16) & 1u);          // round-to-nearest-even
  unsigned short s = (unsigned short)(u >> 16);
  return __builtin_bit_cast(bf16_t, s);
}
__device__ __forceinline__ float bf2f(bf16_t b) {
  unsigned u = ((unsigned)__builtin_bit_cast(unsigned short, b)) << 16;
  return __builtin_bit_cast(float, u);
}

#define MFMA16(a, b, c) __builtin_amdgcn_mfma_f32_16x16x32_bf16((a), (b), (c), 0, 0, 0)

// ---------------------------------------------------------------- zero ----
__global__ __launch_bounds__(256) void tcl_zero(
    int* __restrict__ cnt, int* __restrict__ pos, float* __restrict__ statsrep,
    float* __restrict__ statsfin, int NN)
{
  int t = blockIdx.x * 256 + threadIdx.x;
  if (t < NN) { cnt[t] = 0; pos[t] = 0; }
  if (t < NREP * 64) statsrep[t] = 0.f;
  if (t < 64) statsfin[t] = 0.f;
}

// ------------------------------------------------------- count + wprep ----
// Weights emitted FRAGMENT-MAJOR: elem t = ((((mf*2+half)*4+kg)*16)+l15)*8+e
// holds W[k][n] with n = 16*mf + l15, k = half*32 + kg*8 + e.
__global__ __launch_bounds__(256) void tcl_count(
    const int* __restrict__ eidx, const float* __restrict__ w1,
    const float* __restrict__ w2, unsigned short* __restrict__ w1tg,
    unsigned short* __restrict__ w2tg, int* __restrict__ cnt, int E)
{
  int t = blockIdx.x * 256 + threadIdx.x;
  if (t < E) atomicAdd(&cnt[eidx[E + t]], 1);
  if (t < 64 * 64) {
    int e = t & 7, l15 = (t >> 3) & 15, kg = (t >> 7) & 3, half = (t >> 9) & 1, mf = t >> 10;
    int n = 16 * mf + l15, k = half * 32 + kg * 8 + e;
    w1tg[t] = __builtin_bit_cast(unsigned short, f2bf(w1[k * 64 + n]));
  }
  if (t < 576 * 64) {
    int e = t & 7, l15 = (t >> 3) & 15, kg = (t >> 7) & 3, half = (t >> 9) & 1, mf = t >> 10;
    int n = 16 * mf + l15, k = half * 32 + kg * 8 + e;
    w2tg[t] = __builtin_bit_cast(unsigned short, f2bf(w2[k * 576 + n]));
  }
}

// ---------------------------------------------------------------- scan ----
__global__ __launch_bounds__(1024) void tcl_scan_a(
    const int* __restrict__ cnt, int* __restrict__ excl,
    int* __restrict__ bsum, int NN)
{
  __shared__ int sm[1024];
  int i = blockIdx.x * 1024 + threadIdx.x;
  int v = (i < NN) ? cnt[i] : 0;
  sm[threadIdx.x] = v;
  __syncthreads();
#pragma unroll
  for (int off = 1; off < 1024; off <<= 1) {
    int t = (threadIdx.x >= off) ? sm[threadIdx.x - off] : 0;
    __syncthreads();
    sm[threadIdx.x] += t;
    __syncthreads();
  }
  if (i < NN) excl[i] = sm[threadIdx.x] - v;
  if (threadIdx.x == 1023) bsum[blockIdx.x] = sm[threadIdx.x];
}

__global__ __launch_bounds__(128) void tcl_scan_b(int* __restrict__ bsum, int nb)
{
  __shared__ int sm[128];
  int t = threadIdx.x;
  int v = (t < nb) ? bsum[t] : 0;
  sm[t] = v;
  __syncthreads();
#pragma unroll
  for (int off = 1; off < 128; off <<= 1) {
    int u = (t >= off) ? sm[t - off] : 0;
    __syncthreads();
    sm[t] += u;
    __syncthreads();
  }
  if (t < nb) bsum[t] = sm[t] - v;
}

__global__ __launch_bounds__(256) void tcl_scan_c(
    const int* __restrict__ excl, const int* __restrict__ bsum,
    int* __restrict__ roff, int NN)
{
  int i = blockIdx.x * 256 + threadIdx.x;
  if (i < NN) roff[i] = excl[i] + bsum[i >> 10];
}

// ---------------------------------------------------------------- edge ----
// 768 threads = 12 autonomous waves, 16 edges each. Weights staged in LDS
// fragment-major (zero-conflict sequential ds_read_b128); one barrier.
template <bool SORTED>
__global__ __launch_bounds__(768) void tcl_edge(
    const float* __restrict__ atom, const float* __restrict__ efeat,
    const float* __restrict__ esh, const int* __restrict__ eidx,
    const float* __restrict__ b1, const float* __restrict__ b2,
    const unsigned short* __restrict__ w1tg, const unsigned short* __restrict__ w2tg,
    float* __restrict__ outbuf, int* __restrict__ pos,
    const int* __restrict__ roff, int* __restrict__ cnt, int E)
{
  // ~138.2KB LDS -> 1 block/CU, 12 waves (3/SIMD). VGPR budget ~170: no
  // squeeze on the compiler's natural 128 (R23's 1024-thr block spilled).
  __shared__ __attribute__((aligned(16))) bf16_t w2l[576 * 64];
  __shared__ __attribute__((aligned(16))) bf16_t w1l[64 * 64];
  __shared__ __attribute__((aligned(16))) float  b2l[576];
  __shared__ __attribute__((aligned(16))) float  b1l[64];
  __shared__ __attribute__((aligned(16))) bf16_t hlds[NWV][16][72];
  __shared__ __attribute__((aligned(16))) bf16_t xg[NWV][16][68];

  const int tid  = threadIdx.x;
  const int wv   = tid >> 6;      // wave 0..11 (independent after staging)
  const int lane = tid & 63;
  const int l15  = lane & 15;     // edge in group
  const int kg   = lane >> 4;     // K-slice 0..3
  const int kh   = kg >> 1;
  const int fo   = (l15 << 3);    // fragment elem offset within 128-chunk

  // ---- stage weights once per block (linear dword copy) ----
  {
    const unsigned* s2 = (const unsigned*)w2tg;
    unsigned* d2 = (unsigned*)w2l;
    for (int i = tid; i < 576 * 32; i += 768) d2[i] = s2[i];
    const unsigned* s1 = (const unsigned*)w1tg;
    unsigned* d1 = (unsigned*)w1l;
    for (int i = tid; i < 64 * 32; i += 768) d1[i] = s1[i];
    if (tid < 576) b2l[tid] = b2[tid];
    if (tid < 64) b1l[tid] = b1[tid];
  }
  __syncthreads();                 // the ONLY barrier

  const int ngr = (E + 15) >> 4;
  const int gw0 = blockIdx.x * NWV + wv;
  const int gstride = gridDim.x * NWV;

  for (int g = gw0; g < ngr; g += gstride) {
    long ge = (long)g * 16 + l15;
    bool v = ge < E;

    // ---- A: efeat -> B-fragments direct from global (full K=64 row) ----
    bf16x8 Bf0, Bf1;
    {
      float4 a = {0,0,0,0}, b = a, c = a, d = a;
      if (v) {
        const float4* p = (const float4*)(efeat + ge * 64 + kg * 8);
        a = p[0]; b = p[1];
        const float4* q = (const float4*)(efeat + ge * 64 + 32 + kg * 8);
        c = q[0]; d = q[1];
      }
      Bf0[0]=f2bf(a.x); Bf0[1]=f2bf(a.y); Bf0[2]=f2bf(a.z); Bf0[3]=f2bf(a.w);
      Bf0[4]=f2bf(b.x); Bf0[5]=f2bf(b.y); Bf0[6]=f2bf(b.z); Bf0[7]=f2bf(b.w);
      Bf1[0]=f2bf(c.x); Bf1[1]=f2bf(c.y); Bf1[2]=f2bf(c.z); Bf1[3]=f2bf(c.w);
      Bf1[4]=f2bf(d.x); Bf1[5]=f2bf(d.y); Bf1[6]=f2bf(d.z); Bf1[7]=f2bf(d.w);
    }

    // ---- B: premultiplied TP coefficient table (bf16, work split by kg) ----
    //  [0:16) x0 | [16:40) x1*sh0*c11 | [40:48) (x1.sh1)*c10
    //  [48:64) x0*sh0*c00 | [64:67) sh1*c01
    if (v) {
      int dst = eidx[ge];
      const float* xr = atom + (long)dst * 40;
      const float inv_s2 = 0.70710678118654752f;
      if (kg == 0) {
        for (int i = 0; i < 16; ++i) xg[wv][l15][i] = f2bf(xr[i]);
      } else if (kg == 1) {
        float k11 = esh[ge * 4] * inv_s2 * 0.35355339059327378f;
        for (int t2 = 0; t2 < 24; ++t2) xg[wv][l15][16 + t2] = f2bf(xr[16 + t2] * k11);
      } else if (kg == 2) {
        float s1x = esh[ge * 4 + 1], s1y = esh[ge * 4 + 2], s1z = esh[ge * 4 + 3];
        float k10 = inv_s2 * 0.20412414523193150f;
        for (int i = 0; i < 8; ++i) {
          float y = xr[16 + 3 * i] * s1x + xr[17 + 3 * i] * s1y + xr[18 + 3 * i] * s1z;
          xg[wv][l15][40 + i] = f2bf(y * k10);
        }
        float ks = inv_s2 * 0.25f;
        xg[wv][l15][64] = f2bf(s1x * ks);
        xg[wv][l15][65] = f2bf(s1y * ks);
        xg[wv][l15][66] = f2bf(s1z * ks);
      } else {
        float k0s = esh[ge * 4] * inv_s2 * 0.25f;
        for (int i = 0; i < 16; ++i) xg[wv][l15][48 + i] = f2bf(xr[i] * k0s);
      }
    }

    // ---- C: GEMM1  h = relu(W1T . ef + b1); fragment-major LDS reads ----
    for (int mf = 0; mf < 4; ++mf) {
      bf16x8 a0 = *(const bf16x8*)(w1l + ((mf * 8 + kg) << 7) + fo);
      bf16x8 a1 = *(const bf16x8*)(w1l + ((mf * 8 + 4 + kg) << 7) + fo);
      f32x4 acc = {0.f, 0.f, 0.f, 0.f};
      acc = MFMA16(a0, Bf0, acc);
      acc = MFMA16(a1, Bf1, acc);
      int j0 = 16 * mf + 4 * kg;   // C/D: col=lane&15 (edge), row=(lane>>4)*4+r
      bf16x4 hv;
#pragma unroll
      for (int r = 0; r < 4; ++r) {
        float x = acc[r] + b1l[j0 + r];
        x = x > 0.f ? x : 0.f;
        hv[r] = f2bf(x);
      }
      *(bf16x4*)&hlds[wv][l15][j0] = hv;
    }

    // ---- D: re-read h as B-fragments (same wave; lgkmcnt ordering) ----
    bf16x8 Bh0 = *(const bf16x8*)&hlds[wv][l15][kg * 8];
    bf16x8 Bh1 = *(const bf16x8*)&hlds[wv][l15][32 + kg * 8];
    float s0 = bf2f(xg[wv][l15][64]), s1 = bf2f(xg[wv][l15][65]), s2 = bf2f(xg[wv][l15][66]);

    // ---- E: GEMM2 + TP; fragment-major zero-conflict weight reads ----
    float o0[4] = {};        // out0 slice j = 4*kg + r (complete per lane)
    float o1[4][3] = {};     // out1 slice j = 4*(kg&1) + r (partial: this kh)

    for (int mf = 0; mf < 16; ++mf) {          // w00: i=mf, j=4*kg+r
      bf16x8 a0 = *(const bf16x8*)(w2l + ((mf * 8 + kg) << 7) + fo);
      bf16x8 a1 = *(const bf16x8*)(w2l + ((mf * 8 + 4 + kg) << 7) + fo);
      f32x4 bv = *(const f32x4*)&b2l[16 * mf + 4 * kg];
      f32x4 acc = {0.f, 0.f, 0.f, 0.f};
      acc = MFMA16(a0, Bh0, acc);
      acc = MFMA16(a1, Bh1, acc);
      float cA = bf2f(xg[wv][l15][48 + mf]);
#pragma unroll
      for (int r = 0; r < 4; ++r) o0[r] += (acc[r] + bv[r]) * cA;
    }
    for (int mf = 16; mf < 20; ++mf) {         // w11: i=2*(mf-16)+kh, j=4*(kg&1)+r
      bf16x8 a0 = *(const bf16x8*)(w2l + ((mf * 8 + kg) << 7) + fo);
      bf16x8 a1 = *(const bf16x8*)(w2l + ((mf * 8 + 4 + kg) << 7) + fo);
      f32x4 bv = *(const f32x4*)&b2l[16 * mf + 4 * kg];
      f32x4 acc = {0.f, 0.f, 0.f, 0.f};
      acc = MFMA16(a0, Bh0, acc);
      acc = MFMA16(a1, Bh1, acc);
      int i = 2 * (mf - 16) + kh;
      float c0 = bf2f(xg[wv][l15][16 + 3 * i]), c1 = bf2f(xg[wv][l15][17 + 3 * i]), c2 = bf2f(xg[wv][l15][18 + 3 * i]);
#pragma unroll
      for (int r = 0; r < 4; ++r) {
        float wA = acc[r] + bv[r];
        o1[r][0] += wA * c0; o1[r][1] += wA * c1; o1[r][2] += wA * c2;
      }
    }
    for (int mf = 20; mf < 28; ++mf) {         // w01: i=2*(mf-20)+kh, j=4*(kg&1)+r
      bf16x8 a0 = *(const bf16x8*)(w2l + ((mf * 8 + kg) << 7) + fo);
      bf16x8 a1 = *(const bf16x8*)(w2l + ((mf * 8 + 4 + kg) << 7) + fo);
      f32x4 bv = *(const f32x4*)&b2l[16 * mf + 4 * kg];
      f32x4 acc = {0.f, 0.f, 0.f, 0.f};
      acc = MFMA16(a0, Bh0, acc);
      acc = MFMA16(a1, Bh1, acc);
      int i = 2 * (mf - 20) + kh;
      float xA = bf2f(xg[wv][l15][i]);
#pragma unroll
      for (int r = 0; r < 4; ++r) {
        float tA = (acc[r] + bv[r]) * xA;
        o1[r][0] += tA * s0; o1[r][1] += tA * s1; o1[r][2] += tA * s2;
      }
    }
    for (int mf = 28; mf < 36; ++mf) {         // w10: i=mf-28, j=4*kg+r
      bf16x8 a0 = *(const bf16x8*)(w2l + ((mf * 8 + kg) << 7) + fo);
      bf16x8 a1 = *(const bf16x8*)(w2l + ((mf * 8 + 4 + kg) << 7) + fo);
      f32x4 bv = *(const f32x4*)&b2l[16 * mf + 4 * kg];
      f32x4 acc = {0.f, 0.f, 0.f, 0.f};
      acc = MFMA16(a0, Bh0, acc);
      acc = MFMA16(a1, Bh1, acc);
      float cA = bf2f(xg[wv][l15][40 + mf - 28]);
#pragma unroll
      for (int r = 0; r < 4; ++r) o0[r] += (acc[r] + bv[r]) * cA;
    }

    // fold kh pairs (lane^32: kg<->kg^2, same l15); lanes kg<2 hold full o1
    float o1f[4][3];
#pragma unroll
    for (int r = 0; r < 4; ++r)
#pragma unroll
      for (int c = 0; c < 3; ++c)
        o1f[r][c] = o1[r][c] + __shfl_xor(o1[r][c], 32);

    // ---- F: emit ----
    if (SORTED) {
      int dstrow = 0;
      if (v && kg == 0) {
        int src = eidx[E + ge];
        dstrow = roff[src] + atomicAdd(&pos[src], 1);
      }
      dstrow = __shfl(dstrow, l15);      // lane l15 holds kg==0's ticket
      if (v) {
        float* orow = outbuf + (long)dstrow * 40;
        f32x4 v0 = {o0[0], o0[1], o0[2], o0[3]};
        *(f32x4*)(orow + 4 * kg) = v0;
        if (kg < 2) {
          f32x4 u0 = {o1f[0][0], o1f[0][1], o1f[0][2], o1f[1][0]};
          f32x4 u1 = {o1f[1][1], o1f[1][2], o1f[2][0], o1f[2][1]};
          f32x4 u2 = {o1f[2][2], o1f[3][0], o1f[3][1], o1f[3][2]};
          float* ob = orow + 16 + 12 * kg;
          *(f32x4*)(ob + 0) = u0;
          *(f32x4*)(ob + 4) = u1;
          *(f32x4*)(ob + 8) = u2;
        }
      }
    } else {
      if (v) {
        int src = eidx[E + ge];
        float* srow = outbuf + (long)src * 40;
#pragma unroll
        for (int r = 0; r < 4; ++r) unsafeAtomicAdd(&srow[4 * kg + r], o0[r]);
        if (kg < 2) {
          int j1 = 4 * kg;
#pragma unroll
          for (int r = 0; r < 4; ++r)
#pragma unroll
            for (int c = 0; c < 3; ++c)
              unsafeAtomicAdd(&srow[16 + 3 * (j1 + r) + c], o1f[r][c]);
        }
      }
    }
  }
}

// -------------------------------------------------------- node (gather) ----
// stats atomics striped over NREP replicas (contention /32) + in-wave 3:1
// vsq fold (8 atomics instead of 24 for v channels).
__global__ __launch_bounds__(256) void tcl_node2(
    const float* __restrict__ atom, const float* __restrict__ tp,
    const int* __restrict__ roff, const int* __restrict__ cnt,
    float* __restrict__ out, float* __restrict__ statsrep, int NN)
{
  int lane = threadIdx.x & 63;
  int gw = blockIdx.x * 4 + (threadIdx.x >> 6);
  int stride = gridDim.x * 4;
  float ssum = 0.f, ssq = 0.f, vsq = 0.f;
  for (int n = gw; n < NN; n += stride) {
    int deg = cnt[n];
    long base = roff[n];
    if (lane < 40) {
      float acc = 0.f;
      for (int d = 0; d < deg; ++d) acc += tp[(base + d) * 40 + lane];
      float c = deg > 0 ? (float)deg : 1.f;
      long idx = (long)n * 40 + lane;
      float o = acc / c + atom[idx];
      out[idx] = o;
      if (lane < 16) { ssum += o; ssq += o * o; }
      else           { vsq += o * o; }
    }
  }
  float* srep = statsrep + (long)(blockIdx.x & (NREP - 1)) * 64;
  // fold 3 vector components in-wave: lane 16+3m collects 16+3m+1, 16+3m+2
  float va = __shfl(vsq, lane + 1);
  float vb = __shfl(vsq, lane + 2);
  if (lane < 16) {
    unsafeAtomicAdd(&srep[lane], ssum);
    unsafeAtomicAdd(&srep[16 + lane], ssq);
  } else if (lane < 40 && (lane - 16) % 3 == 0) {
    unsafeAtomicAdd(&srep[32 + (lane - 16) / 3], (vsq + va) + vb);
  }
}

// ------------------------------------------------------------ collapse ----
__global__ __launch_bounds__(64) void tcl_collapse(
    const float* __restrict__ statsrep, float* __restrict__ statsfin)
{
  int c = threadIdx.x;
  float s = 0.f;
  for (int r = 0; r < NREP; ++r) s += statsrep[(long)r * 64 + c];
  statsfin[c] = s;
}

// ---------------------------------------------------- node (atomic path) ----
__global__ __launch_bounds__(256) void tcl_node(
    const float* __restrict__ atom, const int* __restrict__ cnt,
    float* __restrict__ out, float* __restrict__ stats, int NN)
{
  int lane = threadIdx.x & 63;
  int gw = blockIdx.x * 4 + (threadIdx.x >> 6);
  int stride = gridDim.x * 4;
  float ssum = 0.f, ssq = 0.f, vsq = 0.f;
  for (int r = gw; r < NN; r += stride) {
    float c = (float)cnt[r];
    c = c > 1.f ? c : 1.f;
    if (lane < 40) {
      long idx = (long)r * 40 + lane;
      float o = out[idx] / c + atom[idx];
      out[idx] = o;
      if (lane < 16) { ssum += o; ssq += o * o; }
      else           { vsq += o * o; }
    }
  }
  if (lane < 16) {
    unsafeAtomicAdd(&stats[lane], ssum);
    unsafeAtomicAdd(&stats[16 + lane], ssq);
  } else if (lane < 40) {
    unsafeAtomicAdd(&stats[32 + (lane - 16) / 3], vsq);
  }
}

// ---------------------------------------------------------------- norm ----
__global__ __launch_bounds__(256) void tcl_norm(
    float* __restrict__ out, const float* __restrict__ stats,
    const float* __restrict__ bnw, const float* __restrict__ bnb, int NN)
{
  long idx = (long)blockIdx.x * 256 + threadIdx.x;
  long tot = (long)NN * 40;
  if (idx >= tot) return;
  int c = (int)(idx % 40);
  float o = out[idx];
  float invN = 1.0f / (float)NN;
  if (c < 16) {
    float mean = stats[c] * invN;
    float var  = stats[16 + c] * invN - mean * mean;
    float rs   = rsqrtf(var + 1e-5f);
    o = (o - mean) * rs * bnw[c] + bnb[c];
  } else {
    int m = (c - 16) / 3;
    float vn = stats[32 + m] * invN * (1.0f / 3.0f);
    float rs = rsqrtf(vn + 1e-5f);
    o = o * rs * bnw[16 + m];
  }
  out[idx] = o;
}

// -------------------------------------------------------------- launch ----
extern "C" void kernel_launch(void* const* d_in, const int* in_sizes, int n_in,
                              void* d_out, int out_size, void* d_ws, size_t ws_size,
                              hipStream_t stream)
{
  const float* atom  = (const float*)d_in[0];
  const float* efeat = (const float*)d_in[1];
  const float* esh   = (const float*)d_in[2];
  const int*   eidx  = (const int*)d_in[3];
  const float* w1    = (const float*)d_in[4];
  const float* b1    = (const float*)d_in[5];
  const float* w2    = (const float*)d_in[6];
  const float* b2    = (const float*)d_in[7];
  const float* bnw   = (const float*)d_in[8];
  const float* bnb   = (const float*)d_in[9];
  int E  = in_sizes[3] / 2;
  int NN = in_sizes[0] / 40;
  float* out = (float*)d_out;

  // workspace layout (~81.7MB for E=500k, NN=100k; proven fit in R2/R17)
  size_t off = 0;
  auto align256 = [&](size_t o) { return (o + 255) & ~(size_t)255; };
  int* cnt = (int*)d_ws;                                   off += (size_t)NN * 4;
  off = align256(off);
  int* pos = (int*)((char*)d_ws + off);                    off += (size_t)NN * 4;
  off = align256(off);
  int* excl = (int*)((char*)d_ws + off);                   off += (size_t)NN * 4;
  off = align256(off);
  int* bsum = (int*)((char*)d_ws + off);                   off += 128 * 4;
  off = align256(off);
  int* roff = (int*)((char*)d_ws + off);                   off += (size_t)NN * 4;
  off = align256(off);
  float* statsrep = (float*)((char*)d_ws + off);           off += (size_t)NREP * 64 * 4;
  off = align256(off);
  float* statsfin = (float*)((char*)d_ws + off);           off += 64 * 4;
  off = align256(off);
  unsigned short* w1tg = (unsigned short*)((char*)d_ws + off); off += 64 * 64 * 2;
  off = align256(off);
  unsigned short* w2tg = (unsigned short*)((char*)d_ws + off); off += 576 * 64 * 2;
  off = align256(off);
  float* tp = (float*)((char*)d_ws + off);
  size_t need = off + (size_t)E * 40 * 4;

  int nb = (NN + 1023) / 1024;   // scan chunks (<=128)
  bool sorted = (ws_size >= need) && (nb <= 128);

  tcl_zero<<<(NN + 255) / 256, 256, 0, stream>>>(cnt, pos, statsrep, statsfin, NN);
  tcl_count<<<(E + 255) / 256, 256, 0, stream>>>(eidx, w1, w2, w1tg, w2tg, cnt, E);

  if (sorted) {
    tcl_scan_a<<<nb, 1024, 0, stream>>>(cnt, excl, bsum, NN);
    tcl_scan_b<<<1, 128, 0, stream>>>(bsum, nb);
    tcl_scan_c<<<(NN + 255) / 256, 256, 0, stream>>>(excl, bsum, roff, NN);
    tcl_edge<true><<<1024, 768, 0, stream>>>(atom, efeat, esh, eidx, b1, b2,
                                             w1tg, w2tg, tp, pos, roff, cnt, E);
    tcl_node2<<<1024, 256, 0, stream>>>(atom, tp, roff, cnt, out, statsrep, NN);
    tcl_collapse<<<1, 64, 0, stream>>>(statsrep, statsfin);
  } else {
    hipMemsetAsync(d_out, 0, (size_t)NN * 40 * sizeof(float), stream);
    tcl_edge<false><<<1024, 768, 0, stream>>>(atom, efeat, esh, eidx, b1, b2,
                                              w1tg, w2tg, out, pos, roff, cnt, E);
    tcl_node<<<256, 256, 0, stream>>>(atom, cnt, out, statsfin, NN);
  }
  tcl_norm<<<(int)(((long)NN * 40 + 255) / 256), 256, 0, stream>>>(out, statsfin, bnw, bnb, NN);
}

// Round 25
// 360.975 us; speedup vs baseline: 1.6603x; 1.3371x over previous
//
#include <hip/hip_runtime.h>
#include <hip/hip_bf16.h>

// TensorConvLayer: edge MLP (bf16 MFMA) -> tensor product (in-register) ->
// ticketed sorted-row emit (1 int atomic/edge) -> coalesced node gather -> BN.
//
// R24 -> R25: block-size sweep closed -- any block >512 threads squeezes
// VGPR below the natural 128 and spills (R23: 64 VGPR/1.4GB, R24: 84/
// 340MB). Revert to R22's proven optimum (512 thr, 8 waves, VGPR 128,
// edge 219us) + ONE change: next-group software prefetch (T14) -- at group
// g the wave issues g+1's efeat fragments + eidx dst/src + esh float4
// (~+24 VGPR -> ~152, under the 256 cap at 2 waves/SIMD) before computing
// B-F, overlapping next-A HBM latency with current compute. Values
// identical; only load timing moves.

typedef __bf16 bf16_t;
typedef bf16_t bf16x8 __attribute__((ext_vector_type(8)));
typedef bf16_t bf16x4 __attribute__((ext_vector_type(4)));
typedef float  f32x4  __attribute__((ext_vector_type(4)));

#define NREP 32   // stats replicas

__device__ __forceinline__ bf16_t f2bf(float f) {
  unsigned u = __builtin_bit_cast(unsigned, f);
  u += 0x7fffu + ((u >> 16) & 1u);          // round-to-nearest-even
  unsigned short s = (unsigned short)(u >> 16);
  return __builtin_bit_cast(bf16_t, s);
}

#define MFMA16(a, b, c) __builtin_amdgcn_mfma_f32_16x16x32_bf16((a), (b), (c), 0, 0, 0)

// ---------------------------------------------------------------- zero ----
__global__ __launch_bounds__(256) void tcl_zero(
    int* __restrict__ cnt, int* __restrict__ pos, float* __restrict__ statsrep,
    float* __restrict__ statsfin, int NN)
{
  int t = blockIdx.x * 256 + threadIdx.x;
  if (t < NN) { cnt[t] = 0; pos[t] = 0; }
  if (t < NREP * 64) statsrep[t] = 0.f;
  if (t < 64) statsfin[t] = 0.f;
}

// ------------------------------------------------------- count + wprep ----
// Weights emitted FRAGMENT-MAJOR: elem t = ((((mf*2+half)*4+kg)*16)+l15)*8+e
// holds W[k][n] with n = 16*mf + l15, k = half*32 + kg*8 + e.
__global__ __launch_bounds__(256) void tcl_count(
    const int* __restrict__ eidx, const float* __restrict__ w1,
    const float* __restrict__ w2, unsigned short* __restrict__ w1tg,
    unsigned short* __restrict__ w2tg, int* __restrict__ cnt, int E)
{
  int t = blockIdx.x * 256 + threadIdx.x;
  if (t < E) atomicAdd(&cnt[eidx[E + t]], 1);
  if (t < 64 * 64) {
    int e = t & 7, l15 = (t >> 3) & 15, kg = (t >> 7) & 3, half = (t >> 9) & 1, mf = t >> 10;
    int n = 16 * mf + l15, k = half * 32 + kg * 8 + e;
    w1tg[t] = __builtin_bit_cast(unsigned short, f2bf(w1[k * 64 + n]));
  }
  if (t < 576 * 64) {
    int e = t & 7, l15 = (t >> 3) & 15, kg = (t >> 7) & 3, half = (t >> 9) & 1, mf = t >> 10;
    int n = 16 * mf + l15, k = half * 32 + kg * 8 + e;
    w2tg[t] = __builtin_bit_cast(unsigned short, f2bf(w2[k * 576 + n]));
  }
}

// ---------------------------------------------------------------- scan ----
__global__ __launch_bounds__(1024) void tcl_scan_a(
    const int* __restrict__ cnt, int* __restrict__ excl,
    int* __restrict__ bsum, int NN)
{
  __shared__ int sm[1024];
  int i = blockIdx.x * 1024 + threadIdx.x;
  int v = (i < NN) ? cnt[i] : 0;
  sm[threadIdx.x] = v;
  __syncthreads();
#pragma unroll
  for (int off = 1; off < 1024; off <<= 1) {
    int t = (threadIdx.x >= off) ? sm[threadIdx.x - off] : 0;
    __syncthreads();
    sm[threadIdx.x] += t;
    __syncthreads();
  }
  if (i < NN) excl[i] = sm[threadIdx.x] - v;
  if (threadIdx.x == 1023) bsum[blockIdx.x] = sm[threadIdx.x];
}

__global__ __launch_bounds__(128) void tcl_scan_b(int* __restrict__ bsum, int nb)
{
  __shared__ int sm[128];
  int t = threadIdx.x;
  int v = (t < nb) ? bsum[t] : 0;
  sm[t] = v;
  __syncthreads();
#pragma unroll
  for (int off = 1; off < 128; off <<= 1) {
    int u = (t >= off) ? sm[t - off] : 0;
    __syncthreads();
    sm[t] += u;
    __syncthreads();
  }
  if (t < nb) bsum[t] = sm[t] - v;
}

__global__ __launch_bounds__(256) void tcl_scan_c(
    const int* __restrict__ excl, const int* __restrict__ bsum,
    int* __restrict__ roff, int NN)
{
  int i = blockIdx.x * 256 + threadIdx.x;
  if (i < NN) roff[i] = excl[i] + bsum[i >> 10];
}

// ---------------------------------------------------------------- edge ----
// 512 threads = 8 autonomous waves, 16 edges each. Weights staged in LDS
// fragment-major (zero-conflict sequential ds_read_b128); one barrier.
// Grid-stride loop software-pipelined: next group's efeat/eidx/esh loads
// issue before current group's compute.
template <bool SORTED>
__global__ __launch_bounds__(512) void tcl_edge(
    const float* __restrict__ atom, const float* __restrict__ efeat,
    const float* __restrict__ esh, const int* __restrict__ eidx,
    const float* __restrict__ b1, const float* __restrict__ b2,
    const unsigned short* __restrict__ w1tg, const unsigned short* __restrict__ w2tg,
    float* __restrict__ outbuf, int* __restrict__ pos,
    const int* __restrict__ roff, int* __restrict__ cnt, int E)
{
  // ~134.5KB LDS -> 1 block/CU.
  __shared__ __attribute__((aligned(16))) bf16_t w2l[576 * 64];
  __shared__ __attribute__((aligned(16))) bf16_t w1l[64 * 64];
  __shared__ __attribute__((aligned(16))) float  b2l[576];
  __shared__ __attribute__((aligned(16))) float  b1l[64];
  __shared__ __attribute__((aligned(16))) bf16_t hlds[8][16][72];
  __shared__ __attribute__((aligned(16))) float  xg[8][16][68];

  const int tid  = threadIdx.x;
  const int wv   = tid >> 6;      // wave 0..7 (independent after staging)
  const int lane = tid & 63;
  const int l15  = lane & 15;     // edge in group
  const int kg   = lane >> 4;     // K-slice 0..3
  const int kh   = kg >> 1;
  const int fo   = (l15 << 3);    // fragment elem offset within 128-chunk

  // ---- stage weights once per block (linear dword copy) ----
  {
    const unsigned* s2 = (const unsigned*)w2tg;
    unsigned* d2 = (unsigned*)w2l;
    for (int i = tid; i < 576 * 32; i += 512) d2[i] = s2[i];
    const unsigned* s1 = (const unsigned*)w1tg;
    unsigned* d1 = (unsigned*)w1l;
    for (int i = tid; i < 64 * 32; i += 512) d1[i] = s1[i];
    for (int i = tid; i < 576; i += 512) b2l[i] = b2[i];
    if (tid < 64) b1l[tid] = b1[tid];
  }
  __syncthreads();                 // the ONLY barrier

  const int ngr = (E + 15) >> 4;
  const int gw0 = blockIdx.x * 8 + wv;
  const int gstride = gridDim.x * 8;

  // ---- prefetch state for the first group ----
  float4 pa = {0,0,0,0}, pb = pa, pc = pa, pd = pa, pe = pa;
  int pdst = 0, psrc = 0;
  {
    long geP = (long)gw0 * 16 + l15;
    if (gw0 < ngr && geP < E) {
      const float4* p = (const float4*)(efeat + geP * 64 + kg * 8);
      pa = p[0]; pb = p[1];
      const float4* q = (const float4*)(efeat + geP * 64 + 32 + kg * 8);
      pc = q[0]; pd = q[1];
      pe = *(const float4*)(esh + geP * 4);
      pdst = eidx[geP];
      psrc = eidx[E + geP];
    }
  }

  for (int g = gw0; g < ngr; g += gstride) {
    long ge = (long)g * 16 + l15;
    bool v = ge < E;
    // consume prefetched state
    float4 a = pa, b = pb, c = pc, d = pd, e4 = pe;
    int dst = pdst, src = psrc;

    // ---- issue NEXT group's loads (overlap with compute below) ----
    {
      int gn = g + gstride;
      long geN = (long)gn * 16 + l15;
      pa = {0,0,0,0}; pb = pa; pc = pa; pd = pa; pe = pa;
      pdst = 0; psrc = 0;
      if (gn < ngr && geN < E) {
        const float4* p = (const float4*)(efeat + geN * 64 + kg * 8);
        pa = p[0]; pb = p[1];
        const float4* q = (const float4*)(efeat + geN * 64 + 32 + kg * 8);
        pc = q[0]; pd = q[1];
        pe = *(const float4*)(esh + geN * 4);
        pdst = eidx[geN];
        psrc = eidx[E + geN];
      }
    }

    // ---- A: efeat -> B-fragments (from prefetched registers) ----
    bf16x8 Bf0, Bf1;
    Bf0[0]=f2bf(a.x); Bf0[1]=f2bf(a.y); Bf0[2]=f2bf(a.z); Bf0[3]=f2bf(a.w);
    Bf0[4]=f2bf(b.x); Bf0[5]=f2bf(b.y); Bf0[6]=f2bf(b.z); Bf0[7]=f2bf(b.w);
    Bf1[0]=f2bf(c.x); Bf1[1]=f2bf(c.y); Bf1[2]=f2bf(c.z); Bf1[3]=f2bf(c.w);
    Bf1[4]=f2bf(d.x); Bf1[5]=f2bf(d.y); Bf1[6]=f2bf(d.z); Bf1[7]=f2bf(d.w);

    // ---- B: premultiplied TP coefficient table (work split by kg) ----
    //  [0:16) x0 | [16:40) x1*sh0*c11 | [40:48) (x1.sh1)*c10
    //  [48:64) x0*sh0*c00 | [64:67) sh1*c01
    if (v) {
      const float* xr = atom + (long)dst * 40;
      const float inv_s2 = 0.70710678118654752f;
      float sh0 = e4.x;
      if (kg == 0) {
        for (int i = 0; i < 16; ++i) xg[wv][l15][i] = xr[i];
      } else if (kg == 1) {
        float k11 = sh0 * inv_s2 * 0.35355339059327378f;
        for (int t2 = 0; t2 < 24; ++t2) xg[wv][l15][16 + t2] = xr[16 + t2] * k11;
      } else if (kg == 2) {
        float s1x = e4.y, s1y = e4.z, s1z = e4.w;
        float k10 = inv_s2 * 0.20412414523193150f;
        for (int i = 0; i < 8; ++i) {
          float y = xr[16 + 3 * i] * s1x + xr[17 + 3 * i] * s1y + xr[18 + 3 * i] * s1z;
          xg[wv][l15][40 + i] = y * k10;
        }
        float ks = inv_s2 * 0.25f;
        xg[wv][l15][64] = s1x * ks;
        xg[wv][l15][65] = s1y * ks;
        xg[wv][l15][66] = s1z * ks;
      } else {
        float k0s = sh0 * inv_s2 * 0.25f;
        for (int i = 0; i < 16; ++i) xg[wv][l15][48 + i] = xr[i] * k0s;
      }
    }

    // ---- C: GEMM1  h = relu(W1T . ef + b1); fragment-major LDS reads ----
    for (int mf = 0; mf < 4; ++mf) {
      bf16x8 a0 = *(const bf16x8*)(w1l + ((mf * 8 + kg) << 7) + fo);
      bf16x8 a1 = *(const bf16x8*)(w1l + ((mf * 8 + 4 + kg) << 7) + fo);
      f32x4 acc = {0.f, 0.f, 0.f, 0.f};
      acc = MFMA16(a0, Bf0, acc);
      acc = MFMA16(a1, Bf1, acc);
      int j0 = 16 * mf + 4 * kg;   // C/D: col=lane&15 (edge), row=(lane>>4)*4+r
      bf16x4 hv;
#pragma unroll
      for (int r = 0; r < 4; ++r) {
        float x = acc[r] + b1l[j0 + r];
        x = x > 0.f ? x : 0.f;
        hv[r] = f2bf(x);
      }
      *(bf16x4*)&hlds[wv][l15][j0] = hv;
    }

    // ---- D: re-read h as B-fragments (same wave; lgkmcnt ordering) ----
    bf16x8 Bh0 = *(const bf16x8*)&hlds[wv][l15][kg * 8];
    bf16x8 Bh1 = *(const bf16x8*)&hlds[wv][l15][32 + kg * 8];
    float s0 = xg[wv][l15][64], s1 = xg[wv][l15][65], s2 = xg[wv][l15][66];

    // ---- E: GEMM2 + TP; fragment-major zero-conflict weight reads ----
    float o0[4] = {};        // out0 slice j = 4*kg + r (complete per lane)
    float o1[4][3] = {};     // out1 slice j = 4*(kg&1) + r (partial: this kh)

    for (int mf = 0; mf < 16; ++mf) {          // w00: i=mf, j=4*kg+r
      bf16x8 a0 = *(const bf16x8*)(w2l + ((mf * 8 + kg) << 7) + fo);
      bf16x8 a1 = *(const bf16x8*)(w2l + ((mf * 8 + 4 + kg) << 7) + fo);
      f32x4 bv = *(const f32x4*)&b2l[16 * mf + 4 * kg];
      f32x4 acc = {0.f, 0.f, 0.f, 0.f};
      acc = MFMA16(a0, Bh0, acc);
      acc = MFMA16(a1, Bh1, acc);
      float cA = xg[wv][l15][48 + mf];
#pragma unroll
      for (int r = 0; r < 4; ++r) o0[r] += (acc[r] + bv[r]) * cA;
    }
    for (int mf = 16; mf < 20; ++mf) {         // w11: i=2*(mf-16)+kh, j=4*(kg&1)+r
      bf16x8 a0 = *(const bf16x8*)(w2l + ((mf * 8 + kg) << 7) + fo);
      bf16x8 a1 = *(const bf16x8*)(w2l + ((mf * 8 + 4 + kg) << 7) + fo);
      f32x4 bv = *(const f32x4*)&b2l[16 * mf + 4 * kg];
      f32x4 acc = {0.f, 0.f, 0.f, 0.f};
      acc = MFMA16(a0, Bh0, acc);
      acc = MFMA16(a1, Bh1, acc);
      int i = 2 * (mf - 16) + kh;
      float c0 = xg[wv][l15][16 + 3 * i], c1 = xg[wv][l15][17 + 3 * i], c2 = xg[wv][l15][18 + 3 * i];
#pragma unroll
      for (int r = 0; r < 4; ++r) {
        float wA = acc[r] + bv[r];
        o1[r][0] += wA * c0; o1[r][1] += wA * c1; o1[r][2] += wA * c2;
      }
    }
    for (int mf = 20; mf < 28; ++mf) {         // w01: i=2*(mf-20)+kh, j=4*(kg&1)+r
      bf16x8 a0 = *(const bf16x8*)(w2l + ((mf * 8 + kg) << 7) + fo);
      bf16x8 a1 = *(const bf16x8*)(w2l + ((mf * 8 + 4 + kg) << 7) + fo);
      f32x4 bv = *(const f32x4*)&b2l[16 * mf + 4 * kg];
      f32x4 acc = {0.f, 0.f, 0.f, 0.f};
      acc = MFMA16(a0, Bh0, acc);
      acc = MFMA16(a1, Bh1, acc);
      int i = 2 * (mf - 20) + kh;
      float xA = xg[wv][l15][i];
#pragma unroll
      for (int r = 0; r < 4; ++r) {
        float tA = (acc[r] + bv[r]) * xA;
        o1[r][0] += tA * s0; o1[r][1] += tA * s1; o1[r][2] += tA * s2;
      }
    }
    for (int mf = 28; mf < 36; ++mf) {         // w10: i=mf-28, j=4*kg+r
      bf16x8 a0 = *(const bf16x8*)(w2l + ((mf * 8 + kg) << 7) + fo);
      bf16x8 a1 = *(const bf16x8*)(w2l + ((mf * 8 + 4 + kg) << 7) + fo);
      f32x4 bv = *(const f32x4*)&b2l[16 * mf + 4 * kg];
      f32x4 acc = {0.f, 0.f, 0.f, 0.f};
      acc = MFMA16(a0, Bh0, acc);
      acc = MFMA16(a1, Bh1, acc);
      float cA = xg[wv][l15][40 + mf - 28];
#pragma unroll
      for (int r = 0; r < 4; ++r) o0[r] += (acc[r] + bv[r]) * cA;
    }

    // fold kh pairs (lane^32: kg<->kg^2, same l15); lanes kg<2 hold full o1
    float o1f[4][3];
#pragma unroll
    for (int r = 0; r < 4; ++r)
#pragma unroll
      for (int c2 = 0; c2 < 3; ++c2)
        o1f[r][c2] = o1[r][c2] + __shfl_xor(o1[r][c2], 32);

    // ---- F: emit ----
    if (SORTED) {
      int dstrow = 0;
      if (v && kg == 0) {
        dstrow = roff[src] + atomicAdd(&pos[src], 1);
      }
      dstrow = __shfl(dstrow, l15);      // lane l15 holds kg==0's ticket
      if (v) {
        float* orow = outbuf + (long)dstrow * 40;
        f32x4 v0 = {o0[0], o0[1], o0[2], o0[3]};
        *(f32x4*)(orow + 4 * kg) = v0;
        if (kg < 2) {
          f32x4 u0 = {o1f[0][0], o1f[0][1], o1f[0][2], o1f[1][0]};
          f32x4 u1 = {o1f[1][1], o1f[1][2], o1f[2][0], o1f[2][1]};
          f32x4 u2 = {o1f[2][2], o1f[3][0], o1f[3][1], o1f[3][2]};
          float* ob = orow + 16 + 12 * kg;
          *(f32x4*)(ob + 0) = u0;
          *(f32x4*)(ob + 4) = u1;
          *(f32x4*)(ob + 8) = u2;
        }
      }
    } else {
      if (v) {
        float* srow = outbuf + (long)src * 40;
#pragma unroll
        for (int r = 0; r < 4; ++r) unsafeAtomicAdd(&srow[4 * kg + r], o0[r]);
        if (kg < 2) {
          int j1 = 4 * kg;
#pragma unroll
          for (int r = 0; r < 4; ++r)
#pragma unroll
            for (int c2 = 0; c2 < 3; ++c2)
              unsafeAtomicAdd(&srow[16 + 3 * (j1 + r) + c2], o1f[r][c2]);
        }
        if (kg == 0) atomicAdd(&cnt[src], 1);
      }
    }
  }
}

// -------------------------------------------------------- node (gather) ----
// stats atomics striped over NREP replicas (contention /32) + in-wave 3:1
// vsq fold (8 atomics instead of 24 for v channels).
__global__ __launch_bounds__(256) void tcl_node2(
    const float* __restrict__ atom, const float* __restrict__ tp,
    const int* __restrict__ roff, const int* __restrict__ cnt,
    float* __restrict__ out, float* __restrict__ statsrep, int NN)
{
  int lane = threadIdx.x & 63;
  int gw = blockIdx.x * 4 + (threadIdx.x >> 6);
  int stride = gridDim.x * 4;
  float ssum = 0.f, ssq = 0.f, vsq = 0.f;
  for (int n = gw; n < NN; n += stride) {
    int deg = cnt[n];
    long base = roff[n];
    if (lane < 40) {
      float acc = 0.f;
      for (int d = 0; d < deg; ++d) acc += tp[(base + d) * 40 + lane];
      float c = deg > 0 ? (float)deg : 1.f;
      long idx = (long)n * 40 + lane;
      float o = acc / c + atom[idx];
      out[idx] = o;
      if (lane < 16) { ssum += o; ssq += o * o; }
      else           { vsq += o * o; }
    }
  }
  float* srep = statsrep + (long)(blockIdx.x & (NREP - 1)) * 64;
  // fold 3 vector components in-wave: lane 16+3m collects 16+3m+1, 16+3m+2
  float va = __shfl(vsq, lane + 1);
  float vb = __shfl(vsq, lane + 2);
  if (lane < 16) {
    unsafeAtomicAdd(&srep[lane], ssum);
    unsafeAtomicAdd(&srep[16 + lane], ssq);
  } else if (lane < 40 && (lane - 16) % 3 == 0) {
    unsafeAtomicAdd(&srep[32 + (lane - 16) / 3], (vsq + va) + vb);
  }
}

// ------------------------------------------------------------ collapse ----
__global__ __launch_bounds__(64) void tcl_collapse(
    const float* __restrict__ statsrep, float* __restrict__ statsfin)
{
  int c = threadIdx.x;
  float s = 0.f;
  for (int r = 0; r < NREP; ++r) s += statsrep[(long)r * 64 + c];
  statsfin[c] = s;
}

// ---------------------------------------------------- node (atomic path) ----
__global__ __launch_bounds__(256) void tcl_node(
    const float* __restrict__ atom, const int* __restrict__ cnt,
    float* __restrict__ out, float* __restrict__ stats, int NN)
{
  int lane = threadIdx.x & 63;
  int gw = blockIdx.x * 4 + (threadIdx.x >> 6);
  int stride = gridDim.x * 4;
  float ssum = 0.f, ssq = 0.f, vsq = 0.f;
  for (int r = gw; r < NN; r += stride) {
    float c = (float)cnt[r];
    c = c > 1.f ? c : 1.f;
    if (lane < 40) {
      long idx = (long)r * 40 + lane;
      float o = out[idx] / c + atom[idx];
      out[idx] = o;
      if (lane < 16) { ssum += o; ssq += o * o; }
      else           { vsq += o * o; }
    }
  }
  if (lane < 16) {
    unsafeAtomicAdd(&stats[lane], ssum);
    unsafeAtomicAdd(&stats[16 + lane], ssq);
  } else if (lane < 40) {
    unsafeAtomicAdd(&stats[32 + (lane - 16) / 3], vsq);
  }
}

// ---------------------------------------------------------------- norm ----
__global__ __launch_bounds__(256) void tcl_norm(
    float* __restrict__ out, const float* __restrict__ stats,
    const float* __restrict__ bnw, const float* __restrict__ bnb, int NN)
{
  long idx = (long)blockIdx.x * 256 + threadIdx.x;
  long tot = (long)NN * 40;
  if (idx >= tot) return;
  int c = (int)(idx % 40);
  float o = out[idx];
  float invN = 1.0f / (float)NN;
  if (c < 16) {
    float mean = stats[c] * invN;
    float var  = stats[16 + c] * invN - mean * mean;
    float rs   = rsqrtf(var + 1e-5f);
    o = (o - mean) * rs * bnw[c] + bnb[c];
  } else {
    int m = (c - 16) / 3;
    float vn = stats[32 + m] * invN * (1.0f / 3.0f);
    float rs = rsqrtf(vn + 1e-5f);
    o = o * rs * bnw[16 + m];
  }
  out[idx] = o;
}

// -------------------------------------------------------------- launch ----
extern "C" void kernel_launch(void* const* d_in, const int* in_sizes, int n_in,
                              void* d_out, int out_size, void* d_ws, size_t ws_size,
                              hipStream_t stream)
{
  const float* atom  = (const float*)d_in[0];
  const float* efeat = (const float*)d_in[1];
  const float* esh   = (const float*)d_in[2];
  const int*   eidx  = (const int*)d_in[3];
  const float* w1    = (const float*)d_in[4];
  const float* b1    = (const float*)d_in[5];
  const float* w2    = (const float*)d_in[6];
  const float* b2    = (const float*)d_in[7];
  const float* bnw   = (const float*)d_in[8];
  const float* bnb   = (const float*)d_in[9];
  int E  = in_sizes[3] / 2;
  int NN = in_sizes[0] / 40;
  float* out = (float*)d_out;

  // workspace layout (~81.7MB for E=500k, NN=100k; proven fit in R2/R17)
  size_t off = 0;
  auto align256 = [&](size_t o) { return (o + 255) & ~(size_t)255; };
  int* cnt = (int*)d_ws;                                   off += (size_t)NN * 4;
  off = align256(off);
  int* pos = (int*)((char*)d_ws + off);                    off += (size_t)NN * 4;
  off = align256(off);
  int* excl = (int*)((char*)d_ws + off);                   off += (size_t)NN * 4;
  off = align256(off);
  int* bsum = (int*)((char*)d_ws + off);                   off += 128 * 4;
  off = align256(off);
  int* roff = (int*)((char*)d_ws + off);                   off += (size_t)NN * 4;
  off = align256(off);
  float* statsrep = (float*)((char*)d_ws + off);           off += (size_t)NREP * 64 * 4;
  off = align256(off);
  float* statsfin = (float*)((char*)d_ws + off);           off += 64 * 4;
  off = align256(off);
  unsigned short* w1tg = (unsigned short*)((char*)d_ws + off); off += 64 * 64 * 2;
  off = align256(off);
  unsigned short* w2tg = (unsigned short*)((char*)d_ws + off); off += 576 * 64 * 2;
  off = align256(off);
  float* tp = (float*)((char*)d_ws + off);
  size_t need = off + (size_t)E * 40 * 4;

  int nb = (NN + 1023) / 1024;   // scan chunks (<=128)
  bool sorted = (ws_size >= need) && (nb <= 128);

  tcl_zero<<<(NN + 255) / 256, 256, 0, stream>>>(cnt, pos, statsrep, statsfin, NN);
  tcl_count<<<(E + 255) / 256, 256, 0, stream>>>(eidx, w1, w2, w1tg, w2tg, cnt, E);

  if (sorted) {
    tcl_scan_a<<<nb, 1024, 0, stream>>>(cnt, excl, bsum, NN);
    tcl_scan_b<<<1, 128, 0, stream>>>(bsum, nb);
    tcl_scan_c<<<(NN + 255) / 256, 256, 0, stream>>>(excl, bsum, roff, NN);
    tcl_edge<true><<<1024, 512, 0, stream>>>(atom, efeat, esh, eidx, b1, b2,
                                             w1tg, w2tg, tp, pos, roff, cnt, E);
    tcl_node2<<<1024, 256, 0, stream>>>(atom, tp, roff, cnt, out, statsrep, NN);
    tcl_collapse<<<1, 64, 0, stream>>>(statsrep, statsfin);
  } else {
    hipMemsetAsync(d_out, 0, (size_t)NN * 40 * sizeof(float), stream);
    tcl_edge<false><<<1024, 512, 0, stream>>>(atom, efeat, esh, eidx, b1, b2,
                                              w1tg, w2tg, out, pos, roff, cnt, E);
    tcl_node<<<256, 256, 0, stream>>>(atom, cnt, out, statsfin, NN);
  }
  tcl_norm<<<(int)(((long)NN * 40 + 255) / 256), 256, 0, stream>>>(out, statsfin, bnw, bnb, NN);
}

// Round 26
// 293.456 us; speedup vs baseline: 2.0423x; 1.2301x over previous
//
#include <hip/hip_runtime.h>
#include <hip/hip_bf16.h>

// TensorConvLayer: edge MLP (bf16 MFMA) -> tensor product (in-register) ->
// ticketed sorted-row emit (1 int atomic/edge) -> coalesced node gather -> BN.
//
// R25 -> R26: REVERT to the R22 champion (299us total, edge 219us).
// R25's prefetch spilled (FETCH 158->295MB, WRITE ->381MB at fixed VGPR
// 128). Lever ledger complete: unroll-ILP (compiler tightens), reg
// batching (spills), >512-thr blocks (launch_bounds squeeze), prefetch
// (spills) -- all closed. R22 = LDS-staged fragment-major weights,
// 512 thr / 8 autonomous waves / 1 barrier, sorted ticketed emit,
// striped BN stats. This is the structural plateau of this design.

typedef __bf16 bf16_t;
typedef bf16_t bf16x8 __attribute__((ext_vector_type(8)));
typedef bf16_t bf16x4 __attribute__((ext_vector_type(4)));
typedef float  f32x4  __attribute__((ext_vector_type(4)));

#define NREP 32   // stats replicas

__device__ __forceinline__ bf16_t f2bf(float f) {
  unsigned u = __builtin_bit_cast(unsigned, f);
  u += 0x7fffu + ((u >> 16) & 1u);          // round-to-nearest-even
  unsigned short s = (unsigned short)(u >> 16);
  return __builtin_bit_cast(bf16_t, s);
}

#define MFMA16(a, b, c) __builtin_amdgcn_mfma_f32_16x16x32_bf16((a), (b), (c), 0, 0, 0)

// ---------------------------------------------------------------- zero ----
__global__ __launch_bounds__(256) void tcl_zero(
    int* __restrict__ cnt, int* __restrict__ pos, float* __restrict__ statsrep,
    float* __restrict__ statsfin, int NN)
{
  int t = blockIdx.x * 256 + threadIdx.x;
  if (t < NN) { cnt[t] = 0; pos[t] = 0; }
  if (t < NREP * 64) statsrep[t] = 0.f;
  if (t < 64) statsfin[t] = 0.f;
}

// ------------------------------------------------------- count + wprep ----
// Weights emitted FRAGMENT-MAJOR: elem t = ((((mf*2+half)*4+kg)*16)+l15)*8+e
// holds W[k][n] with n = 16*mf + l15, k = half*32 + kg*8 + e.
__global__ __launch_bounds__(256) void tcl_count(
    const int* __restrict__ eidx, const float* __restrict__ w1,
    const float* __restrict__ w2, unsigned short* __restrict__ w1tg,
    unsigned short* __restrict__ w2tg, int* __restrict__ cnt, int E)
{
  int t = blockIdx.x * 256 + threadIdx.x;
  if (t < E) atomicAdd(&cnt[eidx[E + t]], 1);
  if (t < 64 * 64) {
    int e = t & 7, l15 = (t >> 3) & 15, kg = (t >> 7) & 3, half = (t >> 9) & 1, mf = t >> 10;
    int n = 16 * mf + l15, k = half * 32 + kg * 8 + e;
    w1tg[t] = __builtin_bit_cast(unsigned short, f2bf(w1[k * 64 + n]));
  }
  if (t < 576 * 64) {
    int e = t & 7, l15 = (t >> 3) & 15, kg = (t >> 7) & 3, half = (t >> 9) & 1, mf = t >> 10;
    int n = 16 * mf + l15, k = half * 32 + kg * 8 + e;
    w2tg[t] = __builtin_bit_cast(unsigned short, f2bf(w2[k * 576 + n]));
  }
}

// ---------------------------------------------------------------- scan ----
__global__ __launch_bounds__(1024) void tcl_scan_a(
    const int* __restrict__ cnt, int* __restrict__ excl,
    int* __restrict__ bsum, int NN)
{
  __shared__ int sm[1024];
  int i = blockIdx.x * 1024 + threadIdx.x;
  int v = (i < NN) ? cnt[i] : 0;
  sm[threadIdx.x] = v;
  __syncthreads();
#pragma unroll
  for (int off = 1; off < 1024; off <<= 1) {
    int t = (threadIdx.x >= off) ? sm[threadIdx.x - off] : 0;
    __syncthreads();
    sm[threadIdx.x] += t;
    __syncthreads();
  }
  if (i < NN) excl[i] = sm[threadIdx.x] - v;
  if (threadIdx.x == 1023) bsum[blockIdx.x] = sm[threadIdx.x];
}

__global__ __launch_bounds__(128) void tcl_scan_b(int* __restrict__ bsum, int nb)
{
  __shared__ int sm[128];
  int t = threadIdx.x;
  int v = (t < nb) ? bsum[t] : 0;
  sm[t] = v;
  __syncthreads();
#pragma unroll
  for (int off = 1; off < 128; off <<= 1) {
    int u = (t >= off) ? sm[t - off] : 0;
    __syncthreads();
    sm[t] += u;
    __syncthreads();
  }
  if (t < nb) bsum[t] = sm[t] - v;
}

__global__ __launch_bounds__(256) void tcl_scan_c(
    const int* __restrict__ excl, const int* __restrict__ bsum,
    int* __restrict__ roff, int NN)
{
  int i = blockIdx.x * 256 + threadIdx.x;
  if (i < NN) roff[i] = excl[i] + bsum[i >> 10];
}

// ---------------------------------------------------------------- edge ----
// 512 threads = 8 autonomous waves, 16 edges each. Weights staged in LDS
// fragment-major (zero-conflict sequential ds_read_b128); one barrier.
template <bool SORTED>
__global__ __launch_bounds__(512) void tcl_edge(
    const float* __restrict__ atom, const float* __restrict__ efeat,
    const float* __restrict__ esh, const int* __restrict__ eidx,
    const float* __restrict__ b1, const float* __restrict__ b2,
    const unsigned short* __restrict__ w1tg, const unsigned short* __restrict__ w2tg,
    float* __restrict__ outbuf, int* __restrict__ pos,
    const int* __restrict__ roff, int* __restrict__ cnt, int E)
{
  // ~134.5KB LDS -> 1 block/CU.
  __shared__ __attribute__((aligned(16))) bf16_t w2l[576 * 64];
  __shared__ __attribute__((aligned(16))) bf16_t w1l[64 * 64];
  __shared__ __attribute__((aligned(16))) float  b2l[576];
  __shared__ __attribute__((aligned(16))) float  b1l[64];
  __shared__ __attribute__((aligned(16))) bf16_t hlds[8][16][72];
  __shared__ __attribute__((aligned(16))) float  xg[8][16][68];

  const int tid  = threadIdx.x;
  const int wv   = tid >> 6;      // wave 0..7 (independent after staging)
  const int lane = tid & 63;
  const int l15  = lane & 15;     // edge in group
  const int kg   = lane >> 4;     // K-slice 0..3
  const int kh   = kg >> 1;
  const int fo   = (l15 << 3);    // fragment elem offset within 128-chunk

  // ---- stage weights once per block (linear dword copy) ----
  {
    const unsigned* s2 = (const unsigned*)w2tg;
    unsigned* d2 = (unsigned*)w2l;
    for (int i = tid; i < 576 * 32; i += 512) d2[i] = s2[i];
    const unsigned* s1 = (const unsigned*)w1tg;
    unsigned* d1 = (unsigned*)w1l;
    for (int i = tid; i < 64 * 32; i += 512) d1[i] = s1[i];
    for (int i = tid; i < 576; i += 512) b2l[i] = b2[i];
    if (tid < 64) b1l[tid] = b1[tid];
  }
  __syncthreads();                 // the ONLY barrier

  const int ngr = (E + 15) >> 4;
  const int gw0 = blockIdx.x * 8 + wv;
  const int gstride = gridDim.x * 8;

  for (int g = gw0; g < ngr; g += gstride) {
    long ge = (long)g * 16 + l15;
    bool v = ge < E;

    // ---- A: efeat -> B-fragments direct from global (full K=64 row) ----
    bf16x8 Bf0, Bf1;
    {
      float4 a = {0,0,0,0}, b = a, c = a, d = a;
      if (v) {
        const float4* p = (const float4*)(efeat + ge * 64 + kg * 8);
        a = p[0]; b = p[1];
        const float4* q = (const float4*)(efeat + ge * 64 + 32 + kg * 8);
        c = q[0]; d = q[1];
      }
      Bf0[0]=f2bf(a.x); Bf0[1]=f2bf(a.y); Bf0[2]=f2bf(a.z); Bf0[3]=f2bf(a.w);
      Bf0[4]=f2bf(b.x); Bf0[5]=f2bf(b.y); Bf0[6]=f2bf(b.z); Bf0[7]=f2bf(b.w);
      Bf1[0]=f2bf(c.x); Bf1[1]=f2bf(c.y); Bf1[2]=f2bf(c.z); Bf1[3]=f2bf(c.w);
      Bf1[4]=f2bf(d.x); Bf1[5]=f2bf(d.y); Bf1[6]=f2bf(d.z); Bf1[7]=f2bf(d.w);
    }

    // ---- B: premultiplied TP coefficient table (work split by kg) ----
    //  [0:16) x0 | [16:40) x1*sh0*c11 | [40:48) (x1.sh1)*c10
    //  [48:64) x0*sh0*c00 | [64:67) sh1*c01
    if (v) {
      int dst = eidx[ge];
      const float* xr = atom + (long)dst * 40;
      const float inv_s2 = 0.70710678118654752f;
      if (kg == 0) {
        for (int i = 0; i < 16; ++i) xg[wv][l15][i] = xr[i];
      } else if (kg == 1) {
        float k11 = esh[ge * 4] * inv_s2 * 0.35355339059327378f;
        for (int t2 = 0; t2 < 24; ++t2) xg[wv][l15][16 + t2] = xr[16 + t2] * k11;
      } else if (kg == 2) {
        float s1x = esh[ge * 4 + 1], s1y = esh[ge * 4 + 2], s1z = esh[ge * 4 + 3];
        float k10 = inv_s2 * 0.20412414523193150f;
        for (int i = 0; i < 8; ++i) {
          float y = xr[16 + 3 * i] * s1x + xr[17 + 3 * i] * s1y + xr[18 + 3 * i] * s1z;
          xg[wv][l15][40 + i] = y * k10;
        }
        float ks = inv_s2 * 0.25f;
        xg[wv][l15][64] = s1x * ks;
        xg[wv][l15][65] = s1y * ks;
        xg[wv][l15][66] = s1z * ks;
      } else {
        float k0s = esh[ge * 4] * inv_s2 * 0.25f;
        for (int i = 0; i < 16; ++i) xg[wv][l15][48 + i] = xr[i] * k0s;
      }
    }

    // ---- C: GEMM1  h = relu(W1T . ef + b1); fragment-major LDS reads ----
    for (int mf = 0; mf < 4; ++mf) {
      bf16x8 a0 = *(const bf16x8*)(w1l + ((mf * 8 + kg) << 7) + fo);
      bf16x8 a1 = *(const bf16x8*)(w1l + ((mf * 8 + 4 + kg) << 7) + fo);
      f32x4 acc = {0.f, 0.f, 0.f, 0.f};
      acc = MFMA16(a0, Bf0, acc);
      acc = MFMA16(a1, Bf1, acc);
      int j0 = 16 * mf + 4 * kg;   // C/D: col=lane&15 (edge), row=(lane>>4)*4+r
      bf16x4 hv;
#pragma unroll
      for (int r = 0; r < 4; ++r) {
        float x = acc[r] + b1l[j0 + r];
        x = x > 0.f ? x : 0.f;
        hv[r] = f2bf(x);
      }
      *(bf16x4*)&hlds[wv][l15][j0] = hv;
    }

    // ---- D: re-read h as B-fragments (same wave; lgkmcnt ordering) ----
    bf16x8 Bh0 = *(const bf16x8*)&hlds[wv][l15][kg * 8];
    bf16x8 Bh1 = *(const bf16x8*)&hlds[wv][l15][32 + kg * 8];
    float s0 = xg[wv][l15][64], s1 = xg[wv][l15][65], s2 = xg[wv][l15][66];

    // ---- E: GEMM2 + TP; fragment-major zero-conflict weight reads ----
    float o0[4] = {};        // out0 slice j = 4*kg + r (complete per lane)
    float o1[4][3] = {};     // out1 slice j = 4*(kg&1) + r (partial: this kh)

    for (int mf = 0; mf < 16; ++mf) {          // w00: i=mf, j=4*kg+r
      bf16x8 a0 = *(const bf16x8*)(w2l + ((mf * 8 + kg) << 7) + fo);
      bf16x8 a1 = *(const bf16x8*)(w2l + ((mf * 8 + 4 + kg) << 7) + fo);
      f32x4 bv = *(const f32x4*)&b2l[16 * mf + 4 * kg];
      f32x4 acc = {0.f, 0.f, 0.f, 0.f};
      acc = MFMA16(a0, Bh0, acc);
      acc = MFMA16(a1, Bh1, acc);
      float cA = xg[wv][l15][48 + mf];
#pragma unroll
      for (int r = 0; r < 4; ++r) o0[r] += (acc[r] + bv[r]) * cA;
    }
    for (int mf = 16; mf < 20; ++mf) {         // w11: i=2*(mf-16)+kh, j=4*(kg&1)+r
      bf16x8 a0 = *(const bf16x8*)(w2l + ((mf * 8 + kg) << 7) + fo);
      bf16x8 a1 = *(const bf16x8*)(w2l + ((mf * 8 + 4 + kg) << 7) + fo);
      f32x4 bv = *(const f32x4*)&b2l[16 * mf + 4 * kg];
      f32x4 acc = {0.f, 0.f, 0.f, 0.f};
      acc = MFMA16(a0, Bh0, acc);
      acc = MFMA16(a1, Bh1, acc);
      int i = 2 * (mf - 16) + kh;
      float c0 = xg[wv][l15][16 + 3 * i], c1 = xg[wv][l15][17 + 3 * i], c2 = xg[wv][l15][18 + 3 * i];
#pragma unroll
      for (int r = 0; r < 4; ++r) {
        float wA = acc[r] + bv[r];
        o1[r][0] += wA * c0; o1[r][1] += wA * c1; o1[r][2] += wA * c2;
      }
    }
    for (int mf = 20; mf < 28; ++mf) {         // w01: i=2*(mf-20)+kh, j=4*(kg&1)+r
      bf16x8 a0 = *(const bf16x8*)(w2l + ((mf * 8 + kg) << 7) + fo);
      bf16x8 a1 = *(const bf16x8*)(w2l + ((mf * 8 + 4 + kg) << 7) + fo);
      f32x4 bv = *(const f32x4*)&b2l[16 * mf + 4 * kg];
      f32x4 acc = {0.f, 0.f, 0.f, 0.f};
      acc = MFMA16(a0, Bh0, acc);
      acc = MFMA16(a1, Bh1, acc);
      int i = 2 * (mf - 20) + kh;
      float xA = xg[wv][l15][i];
#pragma unroll
      for (int r = 0; r < 4; ++r) {
        float tA = (acc[r] + bv[r]) * xA;
        o1[r][0] += tA * s0; o1[r][1] += tA * s1; o1[r][2] += tA * s2;
      }
    }
    for (int mf = 28; mf < 36; ++mf) {         // w10: i=mf-28, j=4*kg+r
      bf16x8 a0 = *(const bf16x8*)(w2l + ((mf * 8 + kg) << 7) + fo);
      bf16x8 a1 = *(const bf16x8*)(w2l + ((mf * 8 + 4 + kg) << 7) + fo);
      f32x4 bv = *(const f32x4*)&b2l[16 * mf + 4 * kg];
      f32x4 acc = {0.f, 0.f, 0.f, 0.f};
      acc = MFMA16(a0, Bh0, acc);
      acc = MFMA16(a1, Bh1, acc);
      float cA = xg[wv][l15][40 + mf - 28];
#pragma unroll
      for (int r = 0; r < 4; ++r) o0[r] += (acc[r] + bv[r]) * cA;
    }

    // fold kh pairs (lane^32: kg<->kg^2, same l15); lanes kg<2 hold full o1
    float o1f[4][3];
#pragma unroll
    for (int r = 0; r < 4; ++r)
#pragma unroll
      for (int c = 0; c < 3; ++c)
        o1f[r][c] = o1[r][c] + __shfl_xor(o1[r][c], 32);

    // ---- F: emit ----
    if (SORTED) {
      int dstrow = 0;
      if (v && kg == 0) {
        int src = eidx[E + ge];
        dstrow = roff[src] + atomicAdd(&pos[src], 1);
      }
      dstrow = __shfl(dstrow, l15);      // lane l15 holds kg==0's ticket
      if (v) {
        float* orow = outbuf + (long)dstrow * 40;
        f32x4 v0 = {o0[0], o0[1], o0[2], o0[3]};
        *(f32x4*)(orow + 4 * kg) = v0;
        if (kg < 2) {
          f32x4 u0 = {o1f[0][0], o1f[0][1], o1f[0][2], o1f[1][0]};
          f32x4 u1 = {o1f[1][1], o1f[1][2], o1f[2][0], o1f[2][1]};
          f32x4 u2 = {o1f[2][2], o1f[3][0], o1f[3][1], o1f[3][2]};
          float* ob = orow + 16 + 12 * kg;
          *(f32x4*)(ob + 0) = u0;
          *(f32x4*)(ob + 4) = u1;
          *(f32x4*)(ob + 8) = u2;
        }
      }
    } else {
      if (v) {
        int src = eidx[E + ge];
        float* srow = outbuf + (long)src * 40;
#pragma unroll
        for (int r = 0; r < 4; ++r) unsafeAtomicAdd(&srow[4 * kg + r], o0[r]);
        if (kg < 2) {
          int j1 = 4 * kg;
#pragma unroll
          for (int r = 0; r < 4; ++r)
#pragma unroll
            for (int c = 0; c < 3; ++c)
              unsafeAtomicAdd(&srow[16 + 3 * (j1 + r) + c], o1f[r][c]);
        }
        if (kg == 0) atomicAdd(&cnt[src], 1);
      }
    }
  }
}

// -------------------------------------------------------- node (gather) ----
// stats atomics striped over NREP replicas (contention /32) + in-wave 3:1
// vsq fold (8 atomics instead of 24 for v channels).
__global__ __launch_bounds__(256) void tcl_node2(
    const float* __restrict__ atom, const float* __restrict__ tp,
    const int* __restrict__ roff, const int* __restrict__ cnt,
    float* __restrict__ out, float* __restrict__ statsrep, int NN)
{
  int lane = threadIdx.x & 63;
  int gw = blockIdx.x * 4 + (threadIdx.x >> 6);
  int stride = gridDim.x * 4;
  float ssum = 0.f, ssq = 0.f, vsq = 0.f;
  for (int n = gw; n < NN; n += stride) {
    int deg = cnt[n];
    long base = roff[n];
    if (lane < 40) {
      float acc = 0.f;
      for (int d = 0; d < deg; ++d) acc += tp[(base + d) * 40 + lane];
      float c = deg > 0 ? (float)deg : 1.f;
      long idx = (long)n * 40 + lane;
      float o = acc / c + atom[idx];
      out[idx] = o;
      if (lane < 16) { ssum += o; ssq += o * o; }
      else           { vsq += o * o; }
    }
  }
  float* srep = statsrep + (long)(blockIdx.x & (NREP - 1)) * 64;
  // fold 3 vector components in-wave: lane 16+3m collects 16+3m+1, 16+3m+2
  float va = __shfl(vsq, lane + 1);
  float vb = __shfl(vsq, lane + 2);
  if (lane < 16) {
    unsafeAtomicAdd(&srep[lane], ssum);
    unsafeAtomicAdd(&srep[16 + lane], ssq);
  } else if (lane < 40 && (lane - 16) % 3 == 0) {
    unsafeAtomicAdd(&srep[32 + (lane - 16) / 3], (vsq + va) + vb);
  }
}

// ------------------------------------------------------------ collapse ----
__global__ __launch_bounds__(64) void tcl_collapse(
    const float* __restrict__ statsrep, float* __restrict__ statsfin)
{
  int c = threadIdx.x;
  float s = 0.f;
  for (int r = 0; r < NREP; ++r) s += statsrep[(long)r * 64 + c];
  statsfin[c] = s;
}

// ---------------------------------------------------- node (atomic path) ----
__global__ __launch_bounds__(256) void tcl_node(
    const float* __restrict__ atom, const int* __restrict__ cnt,
    float* __restrict__ out, float* __restrict__ stats, int NN)
{
  int lane = threadIdx.x & 63;
  int gw = blockIdx.x * 4 + (threadIdx.x >> 6);
  int stride = gridDim.x * 4;
  float ssum = 0.f, ssq = 0.f, vsq = 0.f;
  for (int r = gw; r < NN; r += stride) {
    float c = (float)cnt[r];
    c = c > 1.f ? c : 1.f;
    if (lane < 40) {
      long idx = (long)r * 40 + lane;
      float o = out[idx] / c + atom[idx];
      out[idx] = o;
      if (lane < 16) { ssum += o; ssq += o * o; }
      else           { vsq += o * o; }
    }
  }
  if (lane < 16) {
    unsafeAtomicAdd(&stats[lane], ssum);
    unsafeAtomicAdd(&stats[16 + lane], ssq);
  } else if (lane < 40) {
    unsafeAtomicAdd(&stats[32 + (lane - 16) / 3], vsq);
  }
}

// ---------------------------------------------------------------- norm ----
__global__ __launch_bounds__(256) void tcl_norm(
    float* __restrict__ out, const float* __restrict__ stats,
    const float* __restrict__ bnw, const float* __restrict__ bnb, int NN)
{
  long idx = (long)blockIdx.x * 256 + threadIdx.x;
  long tot = (long)NN * 40;
  if (idx >= tot) return;
  int c = (int)(idx % 40);
  float o = out[idx];
  float invN = 1.0f / (float)NN;
  if (c < 16) {
    float mean = stats[c] * invN;
    float var  = stats[16 + c] * invN - mean * mean;
    float rs   = rsqrtf(var + 1e-5f);
    o = (o - mean) * rs * bnw[c] + bnb[c];
  } else {
    int m = (c - 16) / 3;
    float vn = stats[32 + m] * invN * (1.0f / 3.0f);
    float rs = rsqrtf(vn + 1e-5f);
    o = o * rs * bnw[16 + m];
  }
  out[idx] = o;
}

// -------------------------------------------------------------- launch ----
extern "C" void kernel_launch(void* const* d_in, const int* in_sizes, int n_in,
                              void* d_out, int out_size, void* d_ws, size_t ws_size,
                              hipStream_t stream)
{
  const float* atom  = (const float*)d_in[0];
  const float* efeat = (const float*)d_in[1];
  const float* esh   = (const float*)d_in[2];
  const int*   eidx  = (const int*)d_in[3];
  const float* w1    = (const float*)d_in[4];
  const float* b1    = (const float*)d_in[5];
  const float* w2    = (const float*)d_in[6];
  const float* b2    = (const float*)d_in[7];
  const float* bnw   = (const float*)d_in[8];
  const float* bnb   = (const float*)d_in[9];
  int E  = in_sizes[3] / 2;
  int NN = in_sizes[0] / 40;
  float* out = (float*)d_out;

  // workspace layout (~81.7MB for E=500k, NN=100k; proven fit in R2/R17)
  size_t off = 0;
  auto align256 = [&](size_t o) { return (o + 255) & ~(size_t)255; };
  int* cnt = (int*)d_ws;                                   off += (size_t)NN * 4;
  off = align256(off);
  int* pos = (int*)((char*)d_ws + off);                    off += (size_t)NN * 4;
  off = align256(off);
  int* excl = (int*)((char*)d_ws + off);                   off += (size_t)NN * 4;
  off = align256(off);
  int* bsum = (int*)((char*)d_ws + off);                   off += 128 * 4;
  off = align256(off);
  int* roff = (int*)((char*)d_ws + off);                   off += (size_t)NN * 4;
  off = align256(off);
  float* statsrep = (float*)((char*)d_ws + off);           off += (size_t)NREP * 64 * 4;
  off = align256(off);
  float* statsfin = (float*)((char*)d_ws + off);           off += 64 * 4;
  off = align256(off);
  unsigned short* w1tg = (unsigned short*)((char*)d_ws + off); off += 64 * 64 * 2;
  off = align256(off);
  unsigned short* w2tg = (unsigned short*)((char*)d_ws + off); off += 576 * 64 * 2;
  off = align256(off);
  float* tp = (float*)((char*)d_ws + off);
  size_t need = off + (size_t)E * 40 * 4;

  int nb = (NN + 1023) / 1024;   // scan chunks (<=128)
  bool sorted = (ws_size >= need) && (nb <= 128);

  tcl_zero<<<(NN + 255) / 256, 256, 0, stream>>>(cnt, pos, statsrep, statsfin, NN);
  tcl_count<<<(E + 255) / 256, 256, 0, stream>>>(eidx, w1, w2, w1tg, w2tg, cnt, E);

  if (sorted) {
    tcl_scan_a<<<nb, 1024, 0, stream>>>(cnt, excl, bsum, NN);
    tcl_scan_b<<<1, 128, 0, stream>>>(bsum, nb);
    tcl_scan_c<<<(NN + 255) / 256, 256, 0, stream>>>(excl, bsum, roff, NN);
    tcl_edge<true><<<1024, 512, 0, stream>>>(atom, efeat, esh, eidx, b1, b2,
                                             w1tg, w2tg, tp, pos, roff, cnt, E);
    tcl_node2<<<1024, 256, 0, stream>>>(atom, tp, roff, cnt, out, statsrep, NN);
    tcl_collapse<<<1, 64, 0, stream>>>(statsrep, statsfin);
  } else {
    hipMemsetAsync(d_out, 0, (size_t)NN * 40 * sizeof(float), stream);
    tcl_edge<false><<<1024, 512, 0, stream>>>(atom, efeat, esh, eidx, b1, b2,
                                              w1tg, w2tg, out, pos, roff, cnt, E);
    tcl_node<<<256, 256, 0, stream>>>(atom, cnt, out, statsfin, NN);
  }
  tcl_norm<<<(int)(((long)NN * 40 + 255) / 256), 256, 0, stream>>>(out, statsfin, bnw, bnb, NN);
}